// Round 1
// baseline (2904.205 us; speedup 1.0000x reference)
//
#include <hip/hip_runtime.h>
#include <math.h>

#define NPTS 6144
#define CH   128

// ---------------------------------------------------------------------------
// Kernel 1: embedding  feat = [corr_feat, centered(kp)] @ W_in + b_in
// ---------------------------------------------------------------------------
__global__ __launch_bounds__(128) void k_embed(
    const float* __restrict__ refp, const float* __restrict__ srcp,
    const float* __restrict__ cf, const float* __restrict__ Win,
    const float* __restrict__ bin, float* __restrict__ out) {
  const int row = blockIdx.x, j = threadIdx.x;
  __shared__ float inb[12];
  __shared__ float mkp;
  if (j < 6)       inb[j] = cf[row * 6 + j];
  else if (j < 9)  inb[j] = refp[row * 3 + (j - 6)];
  else if (j < 12) inb[j] = srcp[row * 3 + (j - 9)];
  __syncthreads();
  if (j == 0) {
    float s = inb[6] + inb[7] + inb[8] + inb[9] + inb[10] + inb[11];
    mkp = s * (1.0f / 6.0f);
  }
  __syncthreads();
  float acc = bin[j];
  #pragma unroll
  for (int kk = 0; kk < 12; kk++) {
    float x = inb[kk] - (kk >= 6 ? mkp : 0.0f);
    acc = fmaf(x, Win[kk * CH + j], acc);
  }
  out[row * CH + j] = acc;
}

// ---------------------------------------------------------------------------
// Kernel 2/5: per-row linear + (residual) + LayerNorm + (leaky relu)
// 128 threads, 4 rows per block
// ---------------------------------------------------------------------------
template <bool RESID, bool LEAKY>
__global__ __launch_bounds__(128) void k_row_linear_ln(
    const float* __restrict__ X, const float* __restrict__ W,
    const float* __restrict__ b, const float* __restrict__ g,
    const float* __restrict__ beta, const float* __restrict__ res,
    float* __restrict__ out) {
  const int j = threadIdx.x;
  const int r0 = blockIdx.x * 4;
  __shared__ float xs[4][CH];
  __shared__ float red[2][4];
  #pragma unroll
  for (int r = 0; r < 4; r++) xs[r][j] = X[(r0 + r) * CH + j];
  __syncthreads();

  float acc[4];
  const float bj = b[j];
  #pragma unroll
  for (int r = 0; r < 4; r++) acc[r] = bj;
  for (int kk = 0; kk < CH; kk++) {
    float w = W[kk * CH + j];
    #pragma unroll
    for (int r = 0; r < 4; r++) acc[r] = fmaf(xs[r][kk], w, acc[r]);
  }
  if (RESID) {
    #pragma unroll
    for (int r = 0; r < 4; r++) acc[r] += res[(r0 + r) * CH + j];
  }

  const int wv = j >> 6, ln = j & 63;
  // mean
  float sum[4];
  #pragma unroll
  for (int r = 0; r < 4; r++) sum[r] = acc[r];
  #pragma unroll
  for (int o = 32; o; o >>= 1) {
    #pragma unroll
    for (int r = 0; r < 4; r++) sum[r] += __shfl_xor(sum[r], o);
  }
  if (ln == 0) {
    #pragma unroll
    for (int r = 0; r < 4; r++) red[wv][r] = sum[r];
  }
  __syncthreads();
  float mean[4], dv[4];
  #pragma unroll
  for (int r = 0; r < 4; r++) {
    mean[r] = (red[0][r] + red[1][r]) * (1.0f / 128.0f);
    dv[r] = acc[r] - mean[r];
    sum[r] = dv[r] * dv[r];
  }
  #pragma unroll
  for (int o = 32; o; o >>= 1) {
    #pragma unroll
    for (int r = 0; r < 4; r++) sum[r] += __shfl_xor(sum[r], o);
  }
  __syncthreads();   // everyone done reading red
  if (ln == 0) {
    #pragma unroll
    for (int r = 0; r < 4; r++) red[wv][r] = sum[r];
  }
  __syncthreads();
  const float gj = g[j], betaj = beta[j];
  #pragma unroll
  for (int r = 0; r < 4; r++) {
    float var = (red[0][r] + red[1][r]) * (1.0f / 128.0f);
    float y = dv[r] * rsqrtf(var + 1e-5f) * gj + betaj;
    if (LEAKY) y = (y > 0.0f) ? y : 0.1f * y;
    out[(r0 + r) * CH + j] = y;
  }
}

// ---------------------------------------------------------------------------
// Kernel 3: fused QKV projection. 128 threads, 4 rows per block.
// ---------------------------------------------------------------------------
__global__ __launch_bounds__(128) void k_qkv(
    const float* __restrict__ X,
    const float* __restrict__ Wq, const float* __restrict__ bq,
    const float* __restrict__ Wk, const float* __restrict__ bk,
    const float* __restrict__ Wv, const float* __restrict__ bv,
    float* __restrict__ Q, float* __restrict__ K, float* __restrict__ V) {
  const int j = threadIdx.x;
  const int r0 = blockIdx.x * 4;
  __shared__ float xs[4][CH];
  #pragma unroll
  for (int r = 0; r < 4; r++) xs[r][j] = X[(r0 + r) * CH + j];
  __syncthreads();
  float aq[4], ak[4], av[4];
  const float bqj = bq[j], bkj = bk[j], bvj = bv[j];
  #pragma unroll
  for (int r = 0; r < 4; r++) { aq[r] = bqj; ak[r] = bkj; av[r] = bvj; }
  for (int kk = 0; kk < CH; kk++) {
    float wq = Wq[kk * CH + j], wk = Wk[kk * CH + j], wv = Wv[kk * CH + j];
    #pragma unroll
    for (int r = 0; r < 4; r++) {
      float x = xs[r][kk];
      aq[r] = fmaf(x, wq, aq[r]);
      ak[r] = fmaf(x, wk, ak[r]);
      av[r] = fmaf(x, wv, av[r]);
    }
  }
  #pragma unroll
  for (int r = 0; r < 4; r++) {
    Q[(r0 + r) * CH + j] = aq[r];
    K[(r0 + r) * CH + j] = ak[r];
    V[(r0 + r) * CH + j] = av[r];
  }
}

// ---------------------------------------------------------------------------
// Kernel 4: fused flash-style attention with on-the-fly geo.
// 256 threads = 4 waves; each wave owns 4 query rows (block = 16 rows).
// Online softmax; K then V staged into one shared tile.
// ---------------------------------------------------------------------------
__global__ __launch_bounds__(256) void k_attn(
    const float* __restrict__ Q, const float* __restrict__ K,
    const float* __restrict__ V,
    const float* __restrict__ refp, const float* __restrict__ srcp,
    float* __restrict__ out) {
  const int tid = threadIdx.x;
  const int wv = tid >> 6, ln = tid & 63;
  const int row0 = blockIdx.x * 16;
  const int wr0 = wv * 4;

  __shared__ float SM[64 * 130];   // K tile (stride 129) then V tile (stride 130)
  __shared__ float qs[16][CH];
  __shared__ float ps[4][4][64];
  __shared__ float cs[64][6];

  for (int idx = tid; idx < 16 * CH; idx += 256)
    qs[idx >> 7][idx & 127] = Q[(row0 + (idx >> 7)) * CH + (idx & 127)];

  float ri[4][3], si[4][3];
  #pragma unroll
  for (int r = 0; r < 4; r++) {
    int gr = row0 + wr0 + r;
    #pragma unroll
    for (int d = 0; d < 3; d++) {
      ri[r][d] = refp[gr * 3 + d];
      si[r][d] = srcp[gr * 3 + d];
    }
  }

  float m[4], l[4], a0[4], a1[4];
  #pragma unroll
  for (int r = 0; r < 4; r++) { m[r] = -1e30f; l[r] = 0.0f; a0[r] = 0.0f; a1[r] = 0.0f; }

  const float scale = 0.08838834764831845f;   // 1/sqrt(128)
  const float invs2 = 1.0f / (0.3f * 0.3f);

  for (int t = 0; t < NPTS / 64; t++) {
    __syncthreads();   // previous V reads complete (also covers qs on t=0)
    for (int idx = tid; idx < 64 * CH; idx += 256) {
      int jj = idx >> 7, c = idx & 127;
      SM[jj * 129 + c] = K[(t * 64 + jj) * CH + c];
    }
    if (tid < 64) {
      int gj = t * 64 + tid;
      cs[tid][0] = refp[gj * 3];     cs[tid][1] = refp[gj * 3 + 1]; cs[tid][2] = refp[gj * 3 + 2];
      cs[tid][3] = srcp[gj * 3];     cs[tid][4] = srcp[gj * 3 + 1]; cs[tid][5] = srcp[gj * 3 + 2];
    }
    __syncthreads();

    // dot products: column ln vs the wave's 4 rows
    float dot[4] = {0.f, 0.f, 0.f, 0.f};
    for (int c = 0; c < CH; c++) {
      float kvv = SM[ln * 129 + c];
      #pragma unroll
      for (int r = 0; r < 4; r++) dot[r] = fmaf(qs[wr0 + r][c], kvv, dot[r]);
    }
    float cj[6];
    #pragma unroll
    for (int d = 0; d < 6; d++) cj[d] = cs[ln][d];

    #pragma unroll
    for (int r = 0; r < 4; r++) {
      float dx = ri[r][0] - cj[0], dy = ri[r][1] - cj[1], dz = ri[r][2] - cj[2];
      float dref = sqrtf(dx * dx + dy * dy + dz * dz);
      dx = si[r][0] - cj[3]; dy = si[r][1] - cj[4]; dz = si[r][2] - cj[5];
      float dsrc = sqrtf(dx * dx + dy * dy + dz * dz);
      float dd = dref - dsrc;
      float gg = fmaxf(1.0f - dd * dd * invs2, 0.0f);
      float logit = gg * dot[r] * scale;

      float tm = logit;
      #pragma unroll
      for (int o = 32; o; o >>= 1) tm = fmaxf(tm, __shfl_xor(tm, o));
      float nm = fmaxf(m[r], tm);
      float rs = __expf(m[r] - nm);
      float p = __expf(logit - nm);
      float pssum = p;
      #pragma unroll
      for (int o = 32; o; o >>= 1) pssum += __shfl_xor(pssum, o);
      l[r] = l[r] * rs + pssum;
      m[r] = nm;
      a0[r] *= rs; a1[r] *= rs;
      ps[wv][r][ln] = p;
    }
    __syncthreads();   // all waves done with K tile
    for (int idx = tid; idx < 64 * CH; idx += 256) {
      int jj = idx >> 7, c = idx & 127;
      SM[jj * 130 + c] = V[(t * 64 + jj) * CH + c];
    }
    __syncthreads();

    for (int jj = 0; jj < 64; jj++) {
      float2 vvv = *(const float2*)&SM[jj * 130 + 2 * ln];
      #pragma unroll
      for (int r = 0; r < 4; r++) {
        float pj = ps[wv][r][jj];
        a0[r] = fmaf(pj, vvv.x, a0[r]);
        a1[r] = fmaf(pj, vvv.y, a1[r]);
      }
    }
  }

  #pragma unroll
  for (int r = 0; r < 4; r++) {
    float invl = 1.0f / l[r];
    int gr = row0 + wr0 + r;
    float2 o2 = make_float2(a0[r] * invl, a1[r] * invl);
    *(float2*)&out[gr * CH + 2 * ln] = o2;
  }
}

// ---------------------------------------------------------------------------
// Kernel 6: final row normalize + classifier MLP + sigmoid
// ---------------------------------------------------------------------------
__global__ __launch_bounds__(128) void k_final(
    const float* __restrict__ F,
    const float* __restrict__ c1W, const float* __restrict__ c1b,
    const float* __restrict__ c2W, const float* __restrict__ c2b,
    const float* __restrict__ c3W, const float* __restrict__ c3b,
    float* __restrict__ out) {
  const int row = blockIdx.x, j = threadIdx.x;
  __shared__ float xs[CH];
  __shared__ float h1[32];
  __shared__ float h2[32];
  __shared__ float red[2];
  float x = F[row * CH + j];
  float ss = x * x;
  #pragma unroll
  for (int o = 32; o; o >>= 1) ss += __shfl_xor(ss, o);
  if ((j & 63) == 0) red[j >> 6] = ss;
  __syncthreads();
  float norm = sqrtf(red[0] + red[1]);
  float xn = x / fmaxf(norm, 1e-12f);
  xs[j] = xn;
  out[row * CH + j] = xn;
  __syncthreads();
  if (j < 32) {
    float a = c1b[j];
    for (int kk = 0; kk < CH; kk++) a = fmaf(xs[kk], c1W[kk * 32 + j], a);
    h1[j] = fmaxf(a, 0.0f);
  }
  __syncthreads();
  if (j < 32) {
    float a = c2b[j];
    #pragma unroll
    for (int kk = 0; kk < 32; kk++) a = fmaf(h1[kk], c2W[kk * 32 + j], a);
    h2[j] = fmaxf(a, 0.0f);
  }
  __syncthreads();
  if (j == 0) {
    float a = c3b[0];
    #pragma unroll
    for (int kk = 0; kk < 32; kk++) a = fmaf(h2[kk], c3W[kk], a);
    out[NPTS * CH + row] = 1.0f / (1.0f + __expf(-a));
  }
}

// ---------------------------------------------------------------------------
extern "C" void kernel_launch(void* const* d_in, const int* in_sizes, int n_in,
                              void* d_out, int out_size, void* d_ws, size_t ws_size,
                              hipStream_t stream) {
  const float* refp = (const float*)d_in[0];
  const float* srcp = (const float*)d_in[1];
  const float* cf   = (const float*)d_in[2];
  const float* Win  = (const float*)d_in[3];
  const float* bin  = (const float*)d_in[4];
  const float* mlpW = (const float*)d_in[5];
  const float* mlpb = (const float*)d_in[6];
  const float* mlpg = (const float*)d_in[7];
  const float* mlpbeta = (const float*)d_in[8];
  const float* Wq = (const float*)d_in[9];
  const float* bq = (const float*)d_in[10];
  const float* Wk = (const float*)d_in[11];
  const float* bk = (const float*)d_in[12];
  const float* Wv = (const float*)d_in[13];
  const float* bv = (const float*)d_in[14];
  const float* Wo = (const float*)d_in[15];
  const float* bo = (const float*)d_in[16];
  const float* lng = (const float*)d_in[17];
  const float* lnb = (const float*)d_in[18];
  const float* c1W = (const float*)d_in[19];
  const float* c1b = (const float*)d_in[20];
  const float* c2W = (const float*)d_in[21];
  const float* c2b = (const float*)d_in[22];
  const float* c3W = (const float*)d_in[23];
  const float* c3b = (const float*)d_in[24];
  float* out = (float*)d_out;

  const size_t NC = (size_t)NPTS * CH;
  float* F = (float*)d_ws;
  float* T = F + NC;
  float* Qb = T + NC;
  float* Kb = Qb + NC;
  float* Vb = Kb + NC;
  float* A = Vb + NC;

  k_embed<<<NPTS, 128, 0, stream>>>(refp, srcp, cf, Win, bin, F);
  for (int i = 0; i < 3; i++) {
    const int o2 = i * CH * CH, o1 = i * CH;
    k_row_linear_ln<false, true><<<NPTS / 4, 128, 0, stream>>>(
        F, mlpW + o2, mlpb + o1, mlpg + o1, mlpbeta + o1, nullptr, T);
    k_qkv<<<NPTS / 4, 128, 0, stream>>>(
        T, Wq + o2, bq + o1, Wk + o2, bk + o1, Wv + o2, bv + o1, Qb, Kb, Vb);
    k_attn<<<NPTS / 16, 256, 0, stream>>>(Qb, Kb, Vb, refp, srcp, A);
    k_row_linear_ln<true, false><<<NPTS / 4, 128, 0, stream>>>(
        A, Wo + o2, bo + o1, lng + o1, lnb + o1, T, F);
  }
  k_final<<<NPTS, 128, 0, stream>>>(F, c1W, c1b, c2W, c2b, c3W, c3b, out);
}

// Round 2
// 1668.637 us; speedup vs baseline: 1.7405x; 1.7405x over previous
//
#include <hip/hip_runtime.h>
#include <math.h>

#define NPTS 6144
#define CH   128

typedef __attribute__((ext_vector_type(8))) short short8;
typedef __attribute__((ext_vector_type(4))) float f32x4;

__device__ inline ushort f2bf(float f) {
  union { float f; unsigned u; } v; v.f = f;
  unsigned u = v.u;
  u += 0x7fff + ((u >> 16) & 1);   // round-to-nearest-even
  return (ushort)(u >> 16);
}

// ---------------------------------------------------------------------------
// Kernel 1: embedding  feat = [corr_feat, centered(kp)] @ W_in + b_in
// ---------------------------------------------------------------------------
__global__ __launch_bounds__(128) void k_embed(
    const float* __restrict__ refp, const float* __restrict__ srcp,
    const float* __restrict__ cf, const float* __restrict__ Win,
    const float* __restrict__ bin, float* __restrict__ out) {
  const int row = blockIdx.x, j = threadIdx.x;
  __shared__ float inb[12];
  __shared__ float mkp;
  if (j < 6)       inb[j] = cf[row * 6 + j];
  else if (j < 9)  inb[j] = refp[row * 3 + (j - 6)];
  else if (j < 12) inb[j] = srcp[row * 3 + (j - 9)];
  __syncthreads();
  if (j == 0) {
    float s = inb[6] + inb[7] + inb[8] + inb[9] + inb[10] + inb[11];
    mkp = s * (1.0f / 6.0f);
  }
  __syncthreads();
  float acc = bin[j];
  #pragma unroll
  for (int kk = 0; kk < 12; kk++) {
    float x = inb[kk] - (kk >= 6 ? mkp : 0.0f);
    acc = fmaf(x, Win[kk * CH + j], acc);
  }
  out[row * CH + j] = acc;
}

// ---------------------------------------------------------------------------
// Kernel 2/5: per-row linear + (residual) + LayerNorm + (leaky relu)
// ---------------------------------------------------------------------------
template <bool RESID, bool LEAKY>
__global__ __launch_bounds__(128) void k_row_linear_ln(
    const float* __restrict__ X, const float* __restrict__ W,
    const float* __restrict__ b, const float* __restrict__ g,
    const float* __restrict__ beta, const float* __restrict__ res,
    float* __restrict__ out) {
  const int j = threadIdx.x;
  const int r0 = blockIdx.x * 4;
  __shared__ float xs[4][CH];
  __shared__ float red[2][4];
  #pragma unroll
  for (int r = 0; r < 4; r++) xs[r][j] = X[(r0 + r) * CH + j];
  __syncthreads();

  float acc[4];
  const float bj = b[j];
  #pragma unroll
  for (int r = 0; r < 4; r++) acc[r] = bj;
  for (int kk = 0; kk < CH; kk++) {
    float w = W[kk * CH + j];
    #pragma unroll
    for (int r = 0; r < 4; r++) acc[r] = fmaf(xs[r][kk], w, acc[r]);
  }
  if (RESID) {
    #pragma unroll
    for (int r = 0; r < 4; r++) acc[r] += res[(r0 + r) * CH + j];
  }

  const int wv = j >> 6, ln = j & 63;
  float sum[4];
  #pragma unroll
  for (int r = 0; r < 4; r++) sum[r] = acc[r];
  #pragma unroll
  for (int o = 32; o; o >>= 1) {
    #pragma unroll
    for (int r = 0; r < 4; r++) sum[r] += __shfl_xor(sum[r], o);
  }
  if (ln == 0) {
    #pragma unroll
    for (int r = 0; r < 4; r++) red[wv][r] = sum[r];
  }
  __syncthreads();
  float mean[4], dv[4];
  #pragma unroll
  for (int r = 0; r < 4; r++) {
    mean[r] = (red[0][r] + red[1][r]) * (1.0f / 128.0f);
    dv[r] = acc[r] - mean[r];
    sum[r] = dv[r] * dv[r];
  }
  #pragma unroll
  for (int o = 32; o; o >>= 1) {
    #pragma unroll
    for (int r = 0; r < 4; r++) sum[r] += __shfl_xor(sum[r], o);
  }
  __syncthreads();
  if (ln == 0) {
    #pragma unroll
    for (int r = 0; r < 4; r++) red[wv][r] = sum[r];
  }
  __syncthreads();
  const float gj = g[j], betaj = beta[j];
  #pragma unroll
  for (int r = 0; r < 4; r++) {
    float var = (red[0][r] + red[1][r]) * (1.0f / 128.0f);
    float y = dv[r] * rsqrtf(var + 1e-5f) * gj + betaj;
    if (LEAKY) y = (y > 0.0f) ? y : 0.1f * y;
    out[(r0 + r) * CH + j] = y;
  }
}

// ---------------------------------------------------------------------------
// Kernel 3: fused QKV projection -> bf16 Q,K row-major; V transposed bf16.
// ---------------------------------------------------------------------------
__global__ __launch_bounds__(128) void k_qkv(
    const float* __restrict__ X,
    const float* __restrict__ Wq, const float* __restrict__ bq,
    const float* __restrict__ Wk, const float* __restrict__ bk,
    const float* __restrict__ Wv, const float* __restrict__ bv,
    ushort* __restrict__ Q, ushort* __restrict__ K, ushort* __restrict__ Vt) {
  const int j = threadIdx.x;
  const int r0 = blockIdx.x * 4;
  __shared__ float xs[4][CH];
  #pragma unroll
  for (int r = 0; r < 4; r++) xs[r][j] = X[(r0 + r) * CH + j];
  __syncthreads();
  float aq[4], ak[4], av[4];
  const float bqj = bq[j], bkj = bk[j], bvj = bv[j];
  #pragma unroll
  for (int r = 0; r < 4; r++) { aq[r] = bqj; ak[r] = bkj; av[r] = bvj; }
  for (int kk = 0; kk < CH; kk++) {
    float wq = Wq[kk * CH + j], wk = Wk[kk * CH + j], wv = Wv[kk * CH + j];
    #pragma unroll
    for (int r = 0; r < 4; r++) {
      float x = xs[r][kk];
      aq[r] = fmaf(x, wq, aq[r]);
      ak[r] = fmaf(x, wk, ak[r]);
      av[r] = fmaf(x, wv, av[r]);
    }
  }
  #pragma unroll
  for (int r = 0; r < 4; r++) {
    Q[(r0 + r) * CH + j] = f2bf(aq[r]);
    K[(r0 + r) * CH + j] = f2bf(ak[r]);
  }
  ushort4 vp;
  vp.x = f2bf(av[0]); vp.y = f2bf(av[1]); vp.z = f2bf(av[2]); vp.w = f2bf(av[3]);
  *(ushort4*)(Vt + (size_t)j * NPTS + r0) = vp;
}

// ---------------------------------------------------------------------------
// Kernel 4: MFMA flash attention with on-the-fly geo.
// 256 threads = 4 waves; wave w owns q-rows [row0+16w, row0+16w+16).
// S = Q@K^T via mfma_f32_16x16x32_bf16; geo+softmax fp32; PV via MFMA.
// ---------------------------------------------------------------------------
__global__ __launch_bounds__(256) void k_attn_mfma(
    const ushort* __restrict__ Q, const ushort* __restrict__ K,
    const ushort* __restrict__ Vt,
    const float* __restrict__ refp, const float* __restrict__ srcp,
    float* __restrict__ out) {
  const int tid = threadIdx.x;
  const int w = tid >> 6, ln = tid & 63;
  const int l15 = ln & 15, g = ln >> 4;
  const int row0 = blockIdx.x * 64;

  __shared__ ushort Ks[64][136];    // K tile, row-major [key][ch], pad->272B stride
  __shared__ ushort Vts[128][72];   // V^T tile [ch][key], pad->144B stride
  __shared__ ushort Ps[4][16][72];  // per-wave P (bf16) [row][key]
  __shared__ float cs[64][6];       // tile keypoint coords

  // Q A-fragments: row = row0+16w+l15, k = 32*ks + 8*g + i  (contiguous 16B)
  short8 qf[4];
  {
    const ushort* qp = Q + (size_t)(row0 + 16 * w + l15) * CH + 8 * g;
    #pragma unroll
    for (int ks = 0; ks < 4; ks++) qf[ks] = *(const short8*)(qp + 32 * ks);
  }
  // coords for the D rows this lane owns: row = row0+16w+4g+r
  float ri[4][3], si[4][3];
  #pragma unroll
  for (int r = 0; r < 4; r++) {
    int gr = row0 + 16 * w + 4 * g + r;
    #pragma unroll
    for (int d = 0; d < 3; d++) {
      ri[r][d] = refp[gr * 3 + d];
      si[r][d] = srcp[gr * 3 + d];
    }
  }

  f32x4 oacc[8];
  #pragma unroll
  for (int n = 0; n < 8; n++) oacc[n] = (f32x4){0.f, 0.f, 0.f, 0.f};
  float m[4], l[4];
  #pragma unroll
  for (int r = 0; r < 4; r++) { m[r] = -1e30f; l[r] = 0.0f; }

  const float scale = 0.08838834764831845f;  // 1/sqrt(128)
  const float invs2 = 1.0f / (0.3f * 0.3f);

  for (int t = 0; t < NPTS / 64; t++) {
    __syncthreads();   // previous tile's LDS reads complete
    #pragma unroll
    for (int s = 0; s < 4; s++) {             // K tile: 64x128 bf16
      int idx = tid + 256 * s;
      int row = idx >> 4, c8 = idx & 15;
      *(short8*)&Ks[row][c8 * 8] =
          *(const short8*)(K + (size_t)(t * 64 + row) * CH + c8 * 8);
    }
    #pragma unroll
    for (int s = 0; s < 4; s++) {             // Vt tile: 128x64 bf16
      int idx = tid + 256 * s;
      int c = idx >> 3, j8 = idx & 7;
      *(short8*)&Vts[c][j8 * 8] =
          *(const short8*)(Vt + (size_t)c * NPTS + t * 64 + j8 * 8);
    }
    if (tid < 64) {
      int gj = t * 64 + tid;
      cs[tid][0] = refp[gj * 3];     cs[tid][1] = refp[gj * 3 + 1];
      cs[tid][2] = refp[gj * 3 + 2]; cs[tid][3] = srcp[gj * 3];
      cs[tid][4] = srcp[gj * 3 + 1]; cs[tid][5] = srcp[gj * 3 + 2];
    }
    __syncthreads();

    // ---- S = Q @ K^T  (16x64 per wave) ----
    f32x4 acc[4];
    #pragma unroll
    for (int nb = 0; nb < 4; nb++) acc[nb] = (f32x4){0.f, 0.f, 0.f, 0.f};
    #pragma unroll
    for (int ks = 0; ks < 4; ks++) {
      #pragma unroll
      for (int nb = 0; nb < 4; nb++) {
        short8 bf = *(const short8*)&Ks[16 * nb + l15][32 * ks + 8 * g];
        acc[nb] = __builtin_amdgcn_mfma_f32_16x16x32_bf16(qf[ks], bf, acc[nb], 0, 0, 0);
      }
    }

    // ---- geo * S * scale, online softmax ----
    float p[4][4];  // [nb][r]
    #pragma unroll
    for (int nb = 0; nb < 4; nb++) {
      int kc = 16 * nb + l15;
      float c0 = cs[kc][0], c1 = cs[kc][1], c2 = cs[kc][2];
      float c3 = cs[kc][3], c4 = cs[kc][4], c5 = cs[kc][5];
      #pragma unroll
      for (int r = 0; r < 4; r++) {
        float dx = ri[r][0] - c0, dy = ri[r][1] - c1, dz = ri[r][2] - c2;
        float dref = sqrtf(dx * dx + dy * dy + dz * dz);
        dx = si[r][0] - c3; dy = si[r][1] - c4; dz = si[r][2] - c5;
        float dsrc = sqrtf(dx * dx + dy * dy + dz * dz);
        float dd = dref - dsrc;
        float gg = fmaxf(1.0f - dd * dd * invs2, 0.0f);
        p[nb][r] = gg * acc[nb][r] * scale;    // logit
      }
    }
    float rm[4], rs[4], sump[4];
    #pragma unroll
    for (int r = 0; r < 4; r++)
      rm[r] = fmaxf(fmaxf(p[0][r], p[1][r]), fmaxf(p[2][r], p[3][r]));
    #pragma unroll
    for (int o = 1; o <= 8; o <<= 1) {
      #pragma unroll
      for (int r = 0; r < 4; r++) rm[r] = fmaxf(rm[r], __shfl_xor(rm[r], o));
    }
    #pragma unroll
    for (int r = 0; r < 4; r++) {
      float nm = fmaxf(m[r], rm[r]);
      rs[r] = __expf(m[r] - nm);
      m[r] = nm;
    }
    #pragma unroll
    for (int nb = 0; nb < 4; nb++)
      #pragma unroll
      for (int r = 0; r < 4; r++) p[nb][r] = __expf(p[nb][r] - m[r]);
    #pragma unroll
    for (int r = 0; r < 4; r++)
      sump[r] = (p[0][r] + p[1][r]) + (p[2][r] + p[3][r]);
    #pragma unroll
    for (int o = 1; o <= 8; o <<= 1) {
      #pragma unroll
      for (int r = 0; r < 4; r++) sump[r] += __shfl_xor(sump[r], o);
    }
    #pragma unroll
    for (int r = 0; r < 4; r++) l[r] = l[r] * rs[r] + sump[r];
    #pragma unroll
    for (int n = 0; n < 8; n++) {
      #pragma unroll
      for (int r = 0; r < 4; r++) oacc[n][r] *= rs[r];
    }
    // stage P as bf16: Ps[w][4g+r][16nb+l15]
    #pragma unroll
    for (int nb = 0; nb < 4; nb++)
      #pragma unroll
      for (int r = 0; r < 4; r++)
        Ps[w][4 * g + r][16 * nb + l15] = f2bf(p[nb][r]);
    __syncthreads();

    // ---- O += P @ V  (A-frag from Ps, B-frag from Vts) ----
    #pragma unroll
    for (int ks2 = 0; ks2 < 2; ks2++) {
      short8 pf = *(const short8*)&Ps[w][l15][32 * ks2 + 8 * g];
      #pragma unroll
      for (int nb2 = 0; nb2 < 8; nb2++) {
        short8 vf = *(const short8*)&Vts[16 * nb2 + l15][32 * ks2 + 8 * g];
        oacc[nb2] = __builtin_amdgcn_mfma_f32_16x16x32_bf16(pf, vf, oacc[nb2], 0, 0, 0);
      }
    }
  }

  #pragma unroll
  for (int r = 0; r < 4; r++) {
    float inv = 1.0f / l[r];
    int gr = row0 + 16 * w + 4 * g + r;
    #pragma unroll
    for (int nb2 = 0; nb2 < 8; nb2++)
      out[(size_t)gr * CH + 16 * nb2 + l15] = oacc[nb2][r] * inv;
  }
}

// ---------------------------------------------------------------------------
// Kernel 6: final row normalize + classifier MLP + sigmoid
// ---------------------------------------------------------------------------
__global__ __launch_bounds__(128) void k_final(
    const float* __restrict__ F,
    const float* __restrict__ c1W, const float* __restrict__ c1b,
    const float* __restrict__ c2W, const float* __restrict__ c2b,
    const float* __restrict__ c3W, const float* __restrict__ c3b,
    float* __restrict__ out) {
  const int row = blockIdx.x, j = threadIdx.x;
  __shared__ float xs[CH];
  __shared__ float h1[32];
  __shared__ float h2[32];
  __shared__ float red[2];
  float x = F[row * CH + j];
  float ss = x * x;
  #pragma unroll
  for (int o = 32; o; o >>= 1) ss += __shfl_xor(ss, o);
  if ((j & 63) == 0) red[j >> 6] = ss;
  __syncthreads();
  float norm = sqrtf(red[0] + red[1]);
  float xn = x / fmaxf(norm, 1e-12f);
  xs[j] = xn;
  out[row * CH + j] = xn;
  __syncthreads();
  if (j < 32) {
    float a = c1b[j];
    for (int kk = 0; kk < CH; kk++) a = fmaf(xs[kk], c1W[kk * 32 + j], a);
    h1[j] = fmaxf(a, 0.0f);
  }
  __syncthreads();
  if (j < 32) {
    float a = c2b[j];
    #pragma unroll
    for (int kk = 0; kk < 32; kk++) a = fmaf(h1[kk], c2W[kk * 32 + j], a);
    h2[j] = fmaxf(a, 0.0f);
  }
  __syncthreads();
  if (j == 0) {
    float a = c3b[0];
    #pragma unroll
    for (int kk = 0; kk < 32; kk++) a = fmaf(h2[kk], c3W[kk], a);
    out[NPTS * CH + row] = 1.0f / (1.0f + __expf(-a));
  }
}

// ---------------------------------------------------------------------------
extern "C" void kernel_launch(void* const* d_in, const int* in_sizes, int n_in,
                              void* d_out, int out_size, void* d_ws, size_t ws_size,
                              hipStream_t stream) {
  const float* refp = (const float*)d_in[0];
  const float* srcp = (const float*)d_in[1];
  const float* cf   = (const float*)d_in[2];
  const float* Win  = (const float*)d_in[3];
  const float* bin  = (const float*)d_in[4];
  const float* mlpW = (const float*)d_in[5];
  const float* mlpb = (const float*)d_in[6];
  const float* mlpg = (const float*)d_in[7];
  const float* mlpbeta = (const float*)d_in[8];
  const float* Wq = (const float*)d_in[9];
  const float* bq = (const float*)d_in[10];
  const float* Wk = (const float*)d_in[11];
  const float* bk = (const float*)d_in[12];
  const float* Wv = (const float*)d_in[13];
  const float* bv = (const float*)d_in[14];
  const float* Wo = (const float*)d_in[15];
  const float* bo = (const float*)d_in[16];
  const float* lng = (const float*)d_in[17];
  const float* lnb = (const float*)d_in[18];
  const float* c1W = (const float*)d_in[19];
  const float* c1b = (const float*)d_in[20];
  const float* c2W = (const float*)d_in[21];
  const float* c2b = (const float*)d_in[22];
  const float* c3W = (const float*)d_in[23];
  const float* c3b = (const float*)d_in[24];
  float* out = (float*)d_out;

  const size_t NC = (size_t)NPTS * CH;
  float* F = (float*)d_ws;
  float* T = F + NC;
  float* A = T + NC;
  ushort* Qb  = (ushort*)(A + NC);
  ushort* Kb  = Qb + NC;
  ushort* Vtb = Kb + NC;

  k_embed<<<NPTS, 128, 0, stream>>>(refp, srcp, cf, Win, bin, F);
  for (int i = 0; i < 3; i++) {
    const int o2 = i * CH * CH, o1 = i * CH;
    k_row_linear_ln<false, true><<<NPTS / 4, 128, 0, stream>>>(
        F, mlpW + o2, mlpb + o1, mlpg + o1, mlpbeta + o1, nullptr, T);
    k_qkv<<<NPTS / 4, 128, 0, stream>>>(
        T, Wq + o2, bq + o1, Wk + o2, bk + o1, Wv + o2, bv + o1, Qb, Kb, Vtb);
    k_attn_mfma<<<NPTS / 64, 256, 0, stream>>>(Qb, Kb, Vtb, refp, srcp, A);
    k_row_linear_ln<true, false><<<NPTS / 4, 128, 0, stream>>>(
        A, Wo + o2, bo + o1, lng + o1, lnb + o1, T, F);
  }
  k_final<<<NPTS, 128, 0, stream>>>(F, c1W, c1b, c2W, c2b, c3W, c3b, out);
}

// Round 3
// 538.307 us; speedup vs baseline: 5.3951x; 3.0998x over previous
//
#include <hip/hip_runtime.h>
#include <math.h>

#define NPTS 6144
#define CH   128

typedef __attribute__((ext_vector_type(8))) short short8;
typedef __attribute__((ext_vector_type(4))) float f32x4;

__device__ inline ushort f2bf(float f) {
  union { float f; unsigned u; } v; v.f = f;
  unsigned u = v.u;
  u += 0x7fff + ((u >> 16) & 1);   // round-to-nearest-even
  return (ushort)(u >> 16);
}

// ---------------------------------------------------------------------------
// Kernel 1: embedding  feat = [corr_feat, centered(kp)] @ W_in + b_in
// ---------------------------------------------------------------------------
__global__ __launch_bounds__(128) void k_embed(
    const float* __restrict__ refp, const float* __restrict__ srcp,
    const float* __restrict__ cf, const float* __restrict__ Win,
    const float* __restrict__ bin, float* __restrict__ out) {
  const int row = blockIdx.x, j = threadIdx.x;
  __shared__ float inb[12];
  __shared__ float mkp;
  if (j < 6)       inb[j] = cf[row * 6 + j];
  else if (j < 9)  inb[j] = refp[row * 3 + (j - 6)];
  else if (j < 12) inb[j] = srcp[row * 3 + (j - 9)];
  __syncthreads();
  if (j == 0) {
    float s = inb[6] + inb[7] + inb[8] + inb[9] + inb[10] + inb[11];
    mkp = s * (1.0f / 6.0f);
  }
  __syncthreads();
  float acc = bin[j];
  #pragma unroll
  for (int kk = 0; kk < 12; kk++) {
    float x = inb[kk] - (kk >= 6 ? mkp : 0.0f);
    acc = fmaf(x, Win[kk * CH + j], acc);
  }
  out[row * CH + j] = acc;
}

// ---------------------------------------------------------------------------
// Kernel 2/5: per-row linear + (residual) + LayerNorm + (leaky relu)
// ---------------------------------------------------------------------------
template <bool RESID, bool LEAKY>
__global__ __launch_bounds__(128) void k_row_linear_ln(
    const float* __restrict__ X, const float* __restrict__ W,
    const float* __restrict__ b, const float* __restrict__ g,
    const float* __restrict__ beta, const float* __restrict__ res,
    float* __restrict__ out) {
  const int j = threadIdx.x;
  const int r0 = blockIdx.x * 4;
  __shared__ float xs[4][CH];
  __shared__ float red[2][4];
  #pragma unroll
  for (int r = 0; r < 4; r++) xs[r][j] = X[(r0 + r) * CH + j];
  __syncthreads();

  float acc[4];
  const float bj = b[j];
  #pragma unroll
  for (int r = 0; r < 4; r++) acc[r] = bj;
  for (int kk = 0; kk < CH; kk++) {
    float w = W[kk * CH + j];
    #pragma unroll
    for (int r = 0; r < 4; r++) acc[r] = fmaf(xs[r][kk], w, acc[r]);
  }
  if (RESID) {
    #pragma unroll
    for (int r = 0; r < 4; r++) acc[r] += res[(r0 + r) * CH + j];
  }

  const int wv = j >> 6, ln = j & 63;
  float sum[4];
  #pragma unroll
  for (int r = 0; r < 4; r++) sum[r] = acc[r];
  #pragma unroll
  for (int o = 32; o; o >>= 1) {
    #pragma unroll
    for (int r = 0; r < 4; r++) sum[r] += __shfl_xor(sum[r], o);
  }
  if (ln == 0) {
    #pragma unroll
    for (int r = 0; r < 4; r++) red[wv][r] = sum[r];
  }
  __syncthreads();
  float mean[4], dv[4];
  #pragma unroll
  for (int r = 0; r < 4; r++) {
    mean[r] = (red[0][r] + red[1][r]) * (1.0f / 128.0f);
    dv[r] = acc[r] - mean[r];
    sum[r] = dv[r] * dv[r];
  }
  #pragma unroll
  for (int o = 32; o; o >>= 1) {
    #pragma unroll
    for (int r = 0; r < 4; r++) sum[r] += __shfl_xor(sum[r], o);
  }
  __syncthreads();
  if (ln == 0) {
    #pragma unroll
    for (int r = 0; r < 4; r++) red[wv][r] = sum[r];
  }
  __syncthreads();
  const float gj = g[j], betaj = beta[j];
  #pragma unroll
  for (int r = 0; r < 4; r++) {
    float var = (red[0][r] + red[1][r]) * (1.0f / 128.0f);
    float y = dv[r] * rsqrtf(var + 1e-5f) * gj + betaj;
    if (LEAKY) y = (y > 0.0f) ? y : 0.1f * y;
    out[(r0 + r) * CH + j] = y;
  }
}

// ---------------------------------------------------------------------------
// Kernel 3: fused QKV projection -> bf16 Q,K row-major; V transposed bf16.
// ---------------------------------------------------------------------------
__global__ __launch_bounds__(128) void k_qkv(
    const float* __restrict__ X,
    const float* __restrict__ Wq, const float* __restrict__ bq,
    const float* __restrict__ Wk, const float* __restrict__ bk,
    const float* __restrict__ Wv, const float* __restrict__ bv,
    ushort* __restrict__ Q, ushort* __restrict__ K, ushort* __restrict__ Vt) {
  const int j = threadIdx.x;
  const int r0 = blockIdx.x * 4;
  __shared__ float xs[4][CH];
  #pragma unroll
  for (int r = 0; r < 4; r++) xs[r][j] = X[(r0 + r) * CH + j];
  __syncthreads();
  float aq[4], ak[4], av[4];
  const float bqj = bq[j], bkj = bk[j], bvj = bv[j];
  #pragma unroll
  for (int r = 0; r < 4; r++) { aq[r] = bqj; ak[r] = bkj; av[r] = bvj; }
  for (int kk = 0; kk < CH; kk++) {
    float wq = Wq[kk * CH + j], wk = Wk[kk * CH + j], wv = Wv[kk * CH + j];
    #pragma unroll
    for (int r = 0; r < 4; r++) {
      float x = xs[r][kk];
      aq[r] = fmaf(x, wq, aq[r]);
      ak[r] = fmaf(x, wk, ak[r]);
      av[r] = fmaf(x, wv, av[r]);
    }
  }
  #pragma unroll
  for (int r = 0; r < 4; r++) {
    Q[(r0 + r) * CH + j] = f2bf(aq[r]);
    K[(r0 + r) * CH + j] = f2bf(ak[r]);
  }
  ushort4 vp;
  vp.x = f2bf(av[0]); vp.y = f2bf(av[1]); vp.z = f2bf(av[2]); vp.w = f2bf(av[3]);
  *(ushort4*)(Vt + (size_t)j * NPTS + r0) = vp;
}

// ---------------------------------------------------------------------------
// Kernel 4: MFMA flash attention, KV-split (flash-decoding style).
// blockIdx.x = q-tile (64 rows), blockIdx.y = KV segment.
// Writes unnormalized partial O + per-row (m, l) to workspace.
// ---------------------------------------------------------------------------
__global__ __launch_bounds__(256) void k_attn_mfma(
    const ushort* __restrict__ Q, const ushort* __restrict__ K,
    const ushort* __restrict__ Vt,
    const float* __restrict__ refp, const float* __restrict__ srcp,
    float* __restrict__ Opart, float* __restrict__ ML, int ntiles) {
  const int tid = threadIdx.x;
  const int w = tid >> 6, ln = tid & 63;
  const int l15 = ln & 15, g = ln >> 4;
  const int row0 = blockIdx.x * 64;
  const int seg = blockIdx.y;
  const int t0 = seg * ntiles;

  __shared__ ushort Ks[64][136];    // K tile, row-major [key][ch]
  __shared__ ushort Vts[128][72];   // V^T tile [ch][key]
  __shared__ ushort Ps[4][16][72];  // per-wave P (bf16) [row][key]
  __shared__ float cs[64][6];       // tile keypoint coords

  // Q A-fragments: row = row0+16w+l15, k = 32*ks + 8*g + i
  short8 qf[4];
  {
    const ushort* qp = Q + (size_t)(row0 + 16 * w + l15) * CH + 8 * g;
    #pragma unroll
    for (int ks = 0; ks < 4; ks++) qf[ks] = *(const short8*)(qp + 32 * ks);
  }
  float ri[4][3], si[4][3];
  #pragma unroll
  for (int r = 0; r < 4; r++) {
    int gr = row0 + 16 * w + 4 * g + r;
    #pragma unroll
    for (int d = 0; d < 3; d++) {
      ri[r][d] = refp[gr * 3 + d];
      si[r][d] = srcp[gr * 3 + d];
    }
  }

  f32x4 oacc[8];
  #pragma unroll
  for (int n = 0; n < 8; n++) oacc[n] = (f32x4){0.f, 0.f, 0.f, 0.f};
  float m[4], l[4];
  #pragma unroll
  for (int r = 0; r < 4; r++) { m[r] = -1e30f; l[r] = 0.0f; }

  const float scale = 0.08838834764831845f;  // 1/sqrt(128)
  const float invs2 = 1.0f / (0.3f * 0.3f);

  for (int tt = 0; tt < ntiles; tt++) {
    const int t = t0 + tt;
    __syncthreads();
    #pragma unroll
    for (int s = 0; s < 4; s++) {             // K tile: 64x128 bf16
      int idx = tid + 256 * s;
      int row = idx >> 4, c8 = idx & 15;
      *(short8*)&Ks[row][c8 * 8] =
          *(const short8*)(K + (size_t)(t * 64 + row) * CH + c8 * 8);
    }
    #pragma unroll
    for (int s = 0; s < 4; s++) {             // Vt tile: 128x64 bf16
      int idx = tid + 256 * s;
      int c = idx >> 3, j8 = idx & 7;
      *(short8*)&Vts[c][j8 * 8] =
          *(const short8*)(Vt + (size_t)c * NPTS + t * 64 + j8 * 8);
    }
    if (tid < 64) {
      int gj = t * 64 + tid;
      cs[tid][0] = refp[gj * 3];     cs[tid][1] = refp[gj * 3 + 1];
      cs[tid][2] = refp[gj * 3 + 2]; cs[tid][3] = srcp[gj * 3];
      cs[tid][4] = srcp[gj * 3 + 1]; cs[tid][5] = srcp[gj * 3 + 2];
    }
    __syncthreads();

    // ---- S = Q @ K^T  (16x64 per wave) ----
    f32x4 acc[4];
    #pragma unroll
    for (int nb = 0; nb < 4; nb++) acc[nb] = (f32x4){0.f, 0.f, 0.f, 0.f};
    #pragma unroll
    for (int ks = 0; ks < 4; ks++) {
      #pragma unroll
      for (int nb = 0; nb < 4; nb++) {
        short8 bf = *(const short8*)&Ks[16 * nb + l15][32 * ks + 8 * g];
        acc[nb] = __builtin_amdgcn_mfma_f32_16x16x32_bf16(qf[ks], bf, acc[nb], 0, 0, 0);
      }
    }

    // ---- geo * S * scale, online softmax ----
    float p[4][4];  // [nb][r]
    #pragma unroll
    for (int nb = 0; nb < 4; nb++) {
      int kc = 16 * nb + l15;
      float c0 = cs[kc][0], c1 = cs[kc][1], c2 = cs[kc][2];
      float c3 = cs[kc][3], c4 = cs[kc][4], c5 = cs[kc][5];
      #pragma unroll
      for (int r = 0; r < 4; r++) {
        float dx = ri[r][0] - c0, dy = ri[r][1] - c1, dz = ri[r][2] - c2;
        float dref = sqrtf(dx * dx + dy * dy + dz * dz);
        dx = si[r][0] - c3; dy = si[r][1] - c4; dz = si[r][2] - c5;
        float dsrc = sqrtf(dx * dx + dy * dy + dz * dz);
        float dd = dref - dsrc;
        float gg = fmaxf(1.0f - dd * dd * invs2, 0.0f);
        p[nb][r] = gg * acc[nb][r] * scale;    // logit
      }
    }
    float rm[4], rs[4], sump[4];
    #pragma unroll
    for (int r = 0; r < 4; r++)
      rm[r] = fmaxf(fmaxf(p[0][r], p[1][r]), fmaxf(p[2][r], p[3][r]));
    #pragma unroll
    for (int o = 1; o <= 8; o <<= 1) {
      #pragma unroll
      for (int r = 0; r < 4; r++) rm[r] = fmaxf(rm[r], __shfl_xor(rm[r], o));
    }
    #pragma unroll
    for (int r = 0; r < 4; r++) {
      float nm = fmaxf(m[r], rm[r]);
      rs[r] = __expf(m[r] - nm);
      m[r] = nm;
    }
    #pragma unroll
    for (int nb = 0; nb < 4; nb++)
      #pragma unroll
      for (int r = 0; r < 4; r++) p[nb][r] = __expf(p[nb][r] - m[r]);
    #pragma unroll
    for (int r = 0; r < 4; r++)
      sump[r] = (p[0][r] + p[1][r]) + (p[2][r] + p[3][r]);
    #pragma unroll
    for (int o = 1; o <= 8; o <<= 1) {
      #pragma unroll
      for (int r = 0; r < 4; r++) sump[r] += __shfl_xor(sump[r], o);
    }
    #pragma unroll
    for (int r = 0; r < 4; r++) l[r] = l[r] * rs[r] + sump[r];
    #pragma unroll
    for (int n = 0; n < 8; n++) {
      #pragma unroll
      for (int r = 0; r < 4; r++) oacc[n][r] *= rs[r];
    }
    #pragma unroll
    for (int nb = 0; nb < 4; nb++)
      #pragma unroll
      for (int r = 0; r < 4; r++)
        Ps[w][4 * g + r][16 * nb + l15] = f2bf(p[nb][r]);
    __syncthreads();

    // ---- O += P @ V ----
    #pragma unroll
    for (int ks2 = 0; ks2 < 2; ks2++) {
      short8 pf = *(const short8*)&Ps[w][l15][32 * ks2 + 8 * g];
      #pragma unroll
      for (int nb2 = 0; nb2 < 8; nb2++) {
        short8 vf = *(const short8*)&Vts[16 * nb2 + l15][32 * ks2 + 8 * g];
        oacc[nb2] = __builtin_amdgcn_mfma_f32_16x16x32_bf16(pf, vf, oacc[nb2], 0, 0, 0);
      }
    }
  }

  // write unnormalized partial + (m, l)
  #pragma unroll
  for (int r = 0; r < 4; r++) {
    int gr = row0 + 16 * w + 4 * g + r;
    float* op = Opart + ((size_t)seg * NPTS + gr) * CH;
    #pragma unroll
    for (int nb2 = 0; nb2 < 8; nb2++)
      op[16 * nb2 + l15] = oacc[nb2][r];
    if (l15 == 0) {
      ML[((size_t)seg * NPTS + gr) * 2]     = m[r];
      ML[((size_t)seg * NPTS + gr) * 2 + 1] = l[r];
    }
  }
}

// ---------------------------------------------------------------------------
// Kernel 4b: combine the NS partials.
// ---------------------------------------------------------------------------
__global__ __launch_bounds__(128) void k_attn_combine(
    const float* __restrict__ Opart, const float* __restrict__ ML,
    float* __restrict__ out, int NS) {
  const int row = blockIdx.x, j = threadIdx.x;
  float M = -1e30f;
  for (int s = 0; s < NS; s++)
    M = fmaxf(M, ML[((size_t)s * NPTS + row) * 2]);
  float L = 0.0f, acc = 0.0f;
  for (int s = 0; s < NS; s++) {
    float ms = ML[((size_t)s * NPTS + row) * 2];
    float ls = ML[((size_t)s * NPTS + row) * 2 + 1];
    float wsc = __expf(ms - M);
    L += wsc * ls;
    acc += wsc * Opart[((size_t)s * NPTS + row) * CH + j];
  }
  out[(size_t)row * CH + j] = acc / L;
}

// ---------------------------------------------------------------------------
// Kernel 6: final row normalize + classifier MLP + sigmoid
// ---------------------------------------------------------------------------
__global__ __launch_bounds__(128) void k_final(
    const float* __restrict__ F,
    const float* __restrict__ c1W, const float* __restrict__ c1b,
    const float* __restrict__ c2W, const float* __restrict__ c2b,
    const float* __restrict__ c3W, const float* __restrict__ c3b,
    float* __restrict__ out) {
  const int row = blockIdx.x, j = threadIdx.x;
  __shared__ float xs[CH];
  __shared__ float h1[32];
  __shared__ float h2[32];
  __shared__ float red[2];
  float x = F[row * CH + j];
  float ss = x * x;
  #pragma unroll
  for (int o = 32; o; o >>= 1) ss += __shfl_xor(ss, o);
  if ((j & 63) == 0) red[j >> 6] = ss;
  __syncthreads();
  float norm = sqrtf(red[0] + red[1]);
  float xn = x / fmaxf(norm, 1e-12f);
  xs[j] = xn;
  out[row * CH + j] = xn;
  __syncthreads();
  if (j < 32) {
    float a = c1b[j];
    for (int kk = 0; kk < CH; kk++) a = fmaf(xs[kk], c1W[kk * 32 + j], a);
    h1[j] = fmaxf(a, 0.0f);
  }
  __syncthreads();
  if (j < 32) {
    float a = c2b[j];
    #pragma unroll
    for (int kk = 0; kk < 32; kk++) a = fmaf(h1[kk], c2W[kk * 32 + j], a);
    h2[j] = fmaxf(a, 0.0f);
  }
  __syncthreads();
  if (j == 0) {
    float a = c3b[0];
    #pragma unroll
    for (int kk = 0; kk < 32; kk++) a = fmaf(h2[kk], c3W[kk], a);
    out[NPTS * CH + row] = 1.0f / (1.0f + __expf(-a));
  }
}

// ---------------------------------------------------------------------------
extern "C" void kernel_launch(void* const* d_in, const int* in_sizes, int n_in,
                              void* d_out, int out_size, void* d_ws, size_t ws_size,
                              hipStream_t stream) {
  const float* refp = (const float*)d_in[0];
  const float* srcp = (const float*)d_in[1];
  const float* cf   = (const float*)d_in[2];
  const float* Win  = (const float*)d_in[3];
  const float* bin  = (const float*)d_in[4];
  const float* mlpW = (const float*)d_in[5];
  const float* mlpb = (const float*)d_in[6];
  const float* mlpg = (const float*)d_in[7];
  const float* mlpbeta = (const float*)d_in[8];
  const float* Wq = (const float*)d_in[9];
  const float* bq = (const float*)d_in[10];
  const float* Wk = (const float*)d_in[11];
  const float* bk = (const float*)d_in[12];
  const float* Wv = (const float*)d_in[13];
  const float* bv = (const float*)d_in[14];
  const float* Wo = (const float*)d_in[15];
  const float* bo = (const float*)d_in[16];
  const float* lng = (const float*)d_in[17];
  const float* lnb = (const float*)d_in[18];
  const float* c1W = (const float*)d_in[19];
  const float* c1b = (const float*)d_in[20];
  const float* c2W = (const float*)d_in[21];
  const float* c2b = (const float*)d_in[22];
  const float* c3W = (const float*)d_in[23];
  const float* c3b = (const float*)d_in[24];
  float* out = (float*)d_out;

  const size_t NC = (size_t)NPTS * CH;
  float* F = (float*)d_ws;
  float* T = F + NC;
  float* A = T + NC;
  ushort* Qb  = (ushort*)(A + NC);
  ushort* Kb  = Qb + NC;
  ushort* Vtb = Kb + NC;
  float* Opart = (float*)(Vtb + NC);

  // pick largest KV-split that fits the workspace
  const size_t base_bytes = 3 * NC * 4 + 3 * NC * 2;
  int NS = 1;
  for (int cand = 16; cand >= 2; cand >>= 1) {
    size_t need = base_bytes + (size_t)cand * (NC * 4 + NPTS * 8);
    if (need <= ws_size) { NS = cand; break; }
  }
  float* ML = Opart + (size_t)NS * NC;
  const int ntiles = NPTS / 64 / NS;

  k_embed<<<NPTS, 128, 0, stream>>>(refp, srcp, cf, Win, bin, F);
  for (int i = 0; i < 3; i++) {
    const int o2 = i * CH * CH, o1 = i * CH;
    k_row_linear_ln<false, true><<<NPTS / 4, 128, 0, stream>>>(
        F, mlpW + o2, mlpb + o1, mlpg + o1, mlpbeta + o1, nullptr, T);
    k_qkv<<<NPTS / 4, 128, 0, stream>>>(
        T, Wq + o2, bq + o1, Wk + o2, bk + o1, Wv + o2, bv + o1, Qb, Kb, Vtb);
    dim3 agrid(NPTS / 64, NS);
    k_attn_mfma<<<agrid, 256, 0, stream>>>(Qb, Kb, Vtb, refp, srcp, Opart, ML, ntiles);
    k_attn_combine<<<NPTS, 128, 0, stream>>>(Opart, ML, A, NS);
    k_row_linear_ln<true, false><<<NPTS / 4, 128, 0, stream>>>(
        A, Wo + o2, bo + o1, lng + o1, lnb + o1, T, F);
  }
  k_final<<<NPTS, 128, 0, stream>>>(F, c1W, c1b, c2W, c2b, c3W, c3b, out);
}

// Round 4
// 466.026 us; speedup vs baseline: 6.2319x; 1.1551x over previous
//
#include <hip/hip_runtime.h>
#include <math.h>

#define NPTS 6144
#define CH   128

typedef __attribute__((ext_vector_type(8))) short short8;
typedef __attribute__((ext_vector_type(4))) float f32x4;
typedef __attribute__((ext_vector_type(2))) float f32x2;
typedef __attribute__((ext_vector_type(4))) int   i32x4;
typedef __attribute__((ext_vector_type(2))) int   i32x2;

__device__ inline ushort f2bf(float f) {
  union { float f; unsigned u; } v; v.f = f;
  unsigned u = v.u;
  u += 0x7fff + ((u >> 16) & 1);   // round-to-nearest-even
  return (ushort)(u >> 16);
}

__device__ inline f32x2 splat2(float x) { return (f32x2){x, x}; }

// ---------------------------------------------------------------------------
// Kernel 1: embedding  feat = [corr_feat, centered(kp)] @ W_in + b_in
// ---------------------------------------------------------------------------
__global__ __launch_bounds__(128) void k_embed(
    const float* __restrict__ refp, const float* __restrict__ srcp,
    const float* __restrict__ cf, const float* __restrict__ Win,
    const float* __restrict__ bin, float* __restrict__ out) {
  const int row = blockIdx.x, j = threadIdx.x;
  __shared__ float inb[12];
  __shared__ float mkp;
  if (j < 6)       inb[j] = cf[row * 6 + j];
  else if (j < 9)  inb[j] = refp[row * 3 + (j - 6)];
  else if (j < 12) inb[j] = srcp[row * 3 + (j - 9)];
  __syncthreads();
  if (j == 0) {
    float s = inb[6] + inb[7] + inb[8] + inb[9] + inb[10] + inb[11];
    mkp = s * (1.0f / 6.0f);
  }
  __syncthreads();
  float acc = bin[j];
  #pragma unroll
  for (int kk = 0; kk < 12; kk++) {
    float x = inb[kk] - (kk >= 6 ? mkp : 0.0f);
    acc = fmaf(x, Win[kk * CH + j], acc);
  }
  out[row * CH + j] = acc;
}

// ---------------------------------------------------------------------------
// Kernel 2/5: per-row linear + (residual) + LayerNorm + (leaky relu)
// ---------------------------------------------------------------------------
template <bool RESID, bool LEAKY>
__global__ __launch_bounds__(128) void k_row_linear_ln(
    const float* __restrict__ X, const float* __restrict__ W,
    const float* __restrict__ b, const float* __restrict__ g,
    const float* __restrict__ beta, const float* __restrict__ res,
    float* __restrict__ out) {
  const int j = threadIdx.x;
  const int r0 = blockIdx.x * 4;
  __shared__ float xs[4][CH];
  __shared__ float red[2][4];
  #pragma unroll
  for (int r = 0; r < 4; r++) xs[r][j] = X[(r0 + r) * CH + j];
  __syncthreads();

  float acc[4];
  const float bj = b[j];
  #pragma unroll
  for (int r = 0; r < 4; r++) acc[r] = bj;
  for (int kk = 0; kk < CH; kk++) {
    float w = W[kk * CH + j];
    #pragma unroll
    for (int r = 0; r < 4; r++) acc[r] = fmaf(xs[r][kk], w, acc[r]);
  }
  if (RESID) {
    #pragma unroll
    for (int r = 0; r < 4; r++) acc[r] += res[(r0 + r) * CH + j];
  }

  const int wv = j >> 6, ln = j & 63;
  float sum[4];
  #pragma unroll
  for (int r = 0; r < 4; r++) sum[r] = acc[r];
  #pragma unroll
  for (int o = 32; o; o >>= 1) {
    #pragma unroll
    for (int r = 0; r < 4; r++) sum[r] += __shfl_xor(sum[r], o);
  }
  if (ln == 0) {
    #pragma unroll
    for (int r = 0; r < 4; r++) red[wv][r] = sum[r];
  }
  __syncthreads();
  float mean[4], dv[4];
  #pragma unroll
  for (int r = 0; r < 4; r++) {
    mean[r] = (red[0][r] + red[1][r]) * (1.0f / 128.0f);
    dv[r] = acc[r] - mean[r];
    sum[r] = dv[r] * dv[r];
  }
  #pragma unroll
  for (int o = 32; o; o >>= 1) {
    #pragma unroll
    for (int r = 0; r < 4; r++) sum[r] += __shfl_xor(sum[r], o);
  }
  __syncthreads();
  if (ln == 0) {
    #pragma unroll
    for (int r = 0; r < 4; r++) red[wv][r] = sum[r];
  }
  __syncthreads();
  const float gj = g[j], betaj = beta[j];
  #pragma unroll
  for (int r = 0; r < 4; r++) {
    float var = (red[0][r] + red[1][r]) * (1.0f / 128.0f);
    float y = dv[r] * rsqrtf(var + 1e-5f) * gj + betaj;
    if (LEAKY) y = (y > 0.0f) ? y : 0.1f * y;
    out[(r0 + r) * CH + j] = y;
  }
}

// ---------------------------------------------------------------------------
// Kernel 3: fused QKV projection -> bf16 Q (pre-scaled by 1/sqrt(C)), K
// row-major; V transposed bf16.
// ---------------------------------------------------------------------------
__global__ __launch_bounds__(128) void k_qkv(
    const float* __restrict__ X,
    const float* __restrict__ Wq, const float* __restrict__ bq,
    const float* __restrict__ Wk, const float* __restrict__ bk,
    const float* __restrict__ Wv, const float* __restrict__ bv,
    ushort* __restrict__ Q, ushort* __restrict__ K, ushort* __restrict__ Vt) {
  const int j = threadIdx.x;
  const int r0 = blockIdx.x * 4;
  __shared__ float xs[4][CH];
  #pragma unroll
  for (int r = 0; r < 4; r++) xs[r][j] = X[(r0 + r) * CH + j];
  __syncthreads();
  float aq[4], ak[4], av[4];
  const float bqj = bq[j], bkj = bk[j], bvj = bv[j];
  #pragma unroll
  for (int r = 0; r < 4; r++) { aq[r] = bqj; ak[r] = bkj; av[r] = bvj; }
  for (int kk = 0; kk < CH; kk++) {
    float wq = Wq[kk * CH + j], wk = Wk[kk * CH + j], wv = Wv[kk * CH + j];
    #pragma unroll
    for (int r = 0; r < 4; r++) {
      float x = xs[r][kk];
      aq[r] = fmaf(x, wq, aq[r]);
      ak[r] = fmaf(x, wk, ak[r]);
      av[r] = fmaf(x, wv, av[r]);
    }
  }
  const float scale = 0.08838834764831845f;  // 1/sqrt(128), folded into Q
  #pragma unroll
  for (int r = 0; r < 4; r++) {
    Q[(r0 + r) * CH + j] = f2bf(aq[r] * scale);
    K[(r0 + r) * CH + j] = f2bf(ak[r]);
  }
  ushort4 vp;
  vp.x = f2bf(av[0]); vp.y = f2bf(av[1]); vp.z = f2bf(av[2]); vp.w = f2bf(av[3]);
  *(ushort4*)(Vt + (size_t)j * NPTS + r0) = vp;
}

// ---------------------------------------------------------------------------
// Kernel 4: MFMA flash attention, KV-split, swapped-QK^T (S^T) so each lane
// owns one q-row; PV uses a key-permuted V^T A-fragment so the P operand is
// the lane's own registers (no LDS round trip, no extra barrier).
// Key permutation: k-slot (ks2, 8g+i)  <->  key 32*ks2 + 16*(i>>2) + 4g + (i&3).
// ---------------------------------------------------------------------------
__global__ __launch_bounds__(256) void k_attn_mfma(
    const ushort* __restrict__ Q, const ushort* __restrict__ K,
    const ushort* __restrict__ Vt,
    const float* __restrict__ refp, const float* __restrict__ srcp,
    float* __restrict__ Opart, float* __restrict__ ML, int ntiles) {
  const int tid = threadIdx.x;
  const int w = tid >> 6, ln = tid & 63;
  const int l15 = ln & 15, g = ln >> 4;
  const int row0 = blockIdx.x * 64;
  const int seg = blockIdx.y;
  const int t0 = seg * ntiles;

  __shared__ ushort Ks[64][136];    // K tile [key][ch], 272B row stride
  __shared__ ushort Vts[128][72];   // V^T tile [ch][key], 144B row stride
  __shared__ float cs2[6][64];      // tile coords, coord-major

  // Q B-fragment: lane (g,l15) provides B[k=8g+i][col=l15] = Q[q0+l15][32ks+8g+i]
  short8 qf[4];
  {
    const ushort* qp = Q + (size_t)(row0 + 16 * w + l15) * CH + 8 * g;
    #pragma unroll
    for (int ks = 0; ks < 4; ks++) qf[ks] = *(const short8*)(qp + 32 * ks);
  }
  // this lane's q-row coords
  const int qrow = row0 + 16 * w + l15;
  const float rq0 = refp[qrow * 3], rq1 = refp[qrow * 3 + 1], rq2 = refp[qrow * 3 + 2];
  const float sq0 = srcp[qrow * 3], sq1 = srcp[qrow * 3 + 1], sq2 = srcp[qrow * 3 + 2];

  f32x4 oacc[8];
  #pragma unroll
  for (int n = 0; n < 8; n++) oacc[n] = (f32x4){0.f, 0.f, 0.f, 0.f};
  float m = -1e30f, l = 0.0f;
  const float invs2 = 1.0f / (0.3f * 0.3f);

  for (int tt = 0; tt < ntiles; tt++) {
    const int t = t0 + tt;
    __syncthreads();
    #pragma unroll
    for (int s = 0; s < 4; s++) {             // K tile: 64x128 bf16
      int idx = tid + 256 * s;
      int row = idx >> 4, c8 = idx & 15;
      *(short8*)&Ks[row][c8 * 8] =
          *(const short8*)(K + (size_t)(t * 64 + row) * CH + c8 * 8);
    }
    #pragma unroll
    for (int s = 0; s < 4; s++) {             // Vt tile: 128x64 bf16
      int idx = tid + 256 * s;
      int c = idx >> 3, j8 = idx & 7;
      *(short8*)&Vts[c][j8 * 8] =
          *(const short8*)(Vt + (size_t)c * NPTS + t * 64 + j8 * 8);
    }
    if (tid < 64) {
      int gj = t * 64 + tid;
      cs2[0][tid] = refp[gj * 3];     cs2[1][tid] = refp[gj * 3 + 1];
      cs2[2][tid] = refp[gj * 3 + 2]; cs2[3][tid] = srcp[gj * 3];
      cs2[4][tid] = srcp[gj * 3 + 1]; cs2[5][tid] = srcp[gj * 3 + 2];
    }
    __syncthreads();

    // ---- S^T = K @ Q^T : lane holds S[q=l15][key=16nb+4g+r] ----
    f32x4 acc[4];
    #pragma unroll
    for (int nb = 0; nb < 4; nb++) acc[nb] = (f32x4){0.f, 0.f, 0.f, 0.f};
    #pragma unroll
    for (int ks = 0; ks < 4; ks++) {
      #pragma unroll
      for (int nb = 0; nb < 4; nb++) {
        short8 af = *(const short8*)&Ks[16 * nb + l15][32 * ks + 8 * g];
        acc[nb] = __builtin_amdgcn_mfma_f32_16x16x32_bf16(af, qf[ks], acc[nb], 0, 0, 0);
      }
    }

    // ---- geo(q, key) * S  (packed f32x2 over key pairs) ----
    float plog[4][4];
    #pragma unroll
    for (int nb = 0; nb < 4; nb++) {
      const int kb = 16 * nb + 4 * g;
      #pragma unroll
      for (int pp = 0; pp < 2; pp++) {
        const int k2 = kb + 2 * pp;
        f32x2 cx = *(const f32x2*)&cs2[0][k2];
        f32x2 cy = *(const f32x2*)&cs2[1][k2];
        f32x2 cz = *(const f32x2*)&cs2[2][k2];
        f32x2 dx = splat2(rq0) - cx, dy = splat2(rq1) - cy, dz = splat2(rq2) - cz;
        f32x2 d2r = dx * dx + dy * dy + dz * dz;
        cx = *(const f32x2*)&cs2[3][k2];
        cy = *(const f32x2*)&cs2[4][k2];
        cz = *(const f32x2*)&cs2[5][k2];
        dx = splat2(sq0) - cx; dy = splat2(sq1) - cy; dz = splat2(sq2) - cz;
        f32x2 d2s = dx * dx + dy * dy + dz * dz;
        f32x2 dr, ds;
        dr[0] = sqrtf(d2r[0]); dr[1] = sqrtf(d2r[1]);
        ds[0] = sqrtf(d2s[0]); ds[1] = sqrtf(d2s[1]);
        f32x2 dd = dr - ds;
        f32x2 tv = splat2(1.0f) - dd * dd * splat2(invs2);
        plog[nb][2 * pp]     = fmaxf(tv[0], 0.0f) * acc[nb][2 * pp];
        plog[nb][2 * pp + 1] = fmaxf(tv[1], 0.0f) * acc[nb][2 * pp + 1];
      }
    }

    // ---- online softmax (scalar per lane; cross-g reduce only) ----
    float tm = plog[0][0];
    #pragma unroll
    for (int nb = 0; nb < 4; nb++)
      #pragma unroll
      for (int r = 0; r < 4; r++) tm = fmaxf(tm, plog[nb][r]);
    tm = fmaxf(tm, __shfl_xor(tm, 16));
    tm = fmaxf(tm, __shfl_xor(tm, 32));
    float nm = fmaxf(m, tm);
    if (__any(nm > m)) {
      float rsc = __expf(m - nm);
      l *= rsc;
      #pragma unroll
      for (int n = 0; n < 8; n++) oacc[n] *= rsc;
      m = nm;
    }
    float psum = 0.0f;
    #pragma unroll
    for (int nb = 0; nb < 4; nb++)
      #pragma unroll
      for (int r = 0; r < 4; r++) {
        float p = __expf(plog[nb][r] - m);
        plog[nb][r] = p;
        psum += p;
      }
    psum += __shfl_xor(psum, 16);
    psum += __shfl_xor(psum, 32);
    l += psum;

    // ---- pack P to bf16 pairs (lane-local PV B-fragment) ----
    unsigned pk[4][2];
    #pragma unroll
    for (int nb = 0; nb < 4; nb++) {
      asm("v_cvt_pk_bf16_f32 %0, %1, %2"
          : "=v"(pk[nb][0]) : "v"(plog[nb][0]), "v"(plog[nb][1]));
      asm("v_cvt_pk_bf16_f32 %0, %1, %2"
          : "=v"(pk[nb][1]) : "v"(plog[nb][2]), "v"(plog[nb][3]));
    }

    // ---- O^T += V^T(permuted) @ P^T ----
    union U16 { i32x4 i; short8 s; };
    #pragma unroll
    for (int ks2 = 0; ks2 < 2; ks2++) {
      U16 b;
      b.i[0] = (int)pk[2 * ks2][0];
      b.i[1] = (int)pk[2 * ks2][1];
      b.i[2] = (int)pk[2 * ks2 + 1][0];
      b.i[3] = (int)pk[2 * ks2 + 1][1];
      #pragma unroll
      for (int nb2 = 0; nb2 < 8; nb2++) {
        const ushort* vp2 = &Vts[16 * nb2 + l15][32 * ks2 + 4 * g];
        i32x2 a0 = *(const i32x2*)vp2;
        i32x2 a1 = *(const i32x2*)(vp2 + 16);
        U16 a;
        a.i[0] = a0[0]; a.i[1] = a0[1]; a.i[2] = a1[0]; a.i[3] = a1[1];
        oacc[nb2] = __builtin_amdgcn_mfma_f32_16x16x32_bf16(a.s, b.s, oacc[nb2], 0, 0, 0);
      }
    }
  }

  // write unnormalized partial + (m, l);  lane holds O[q=l15][d=16nb2+4g+r]
  {
    float* op = Opart + ((size_t)seg * NPTS + qrow) * CH;
    #pragma unroll
    for (int nb2 = 0; nb2 < 8; nb2++)
      *(f32x4*)(op + 16 * nb2 + 4 * g) = oacc[nb2];
    if (g == 0) {
      ML[((size_t)seg * NPTS + qrow) * 2]     = m;
      ML[((size_t)seg * NPTS + qrow) * 2 + 1] = l;
    }
  }
}

// ---------------------------------------------------------------------------
// Kernel 4b: combine the NS partials.
// ---------------------------------------------------------------------------
__global__ __launch_bounds__(128) void k_attn_combine(
    const float* __restrict__ Opart, const float* __restrict__ ML,
    float* __restrict__ out, int NS) {
  const int row = blockIdx.x, j = threadIdx.x;
  float M = -1e30f;
  for (int s = 0; s < NS; s++)
    M = fmaxf(M, ML[((size_t)s * NPTS + row) * 2]);
  float L = 0.0f, acc = 0.0f;
  for (int s = 0; s < NS; s++) {
    float ms = ML[((size_t)s * NPTS + row) * 2];
    float ls = ML[((size_t)s * NPTS + row) * 2 + 1];
    float wsc = __expf(ms - M);
    L += wsc * ls;
    acc += wsc * Opart[((size_t)s * NPTS + row) * CH + j];
  }
  out[(size_t)row * CH + j] = acc / L;
}

// ---------------------------------------------------------------------------
// Kernel 6: final row normalize + classifier MLP + sigmoid
// ---------------------------------------------------------------------------
__global__ __launch_bounds__(128) void k_final(
    const float* __restrict__ F,
    const float* __restrict__ c1W, const float* __restrict__ c1b,
    const float* __restrict__ c2W, const float* __restrict__ c2b,
    const float* __restrict__ c3W, const float* __restrict__ c3b,
    float* __restrict__ out) {
  const int row = blockIdx.x, j = threadIdx.x;
  __shared__ float xs[CH];
  __shared__ float h1[32];
  __shared__ float h2[32];
  __shared__ float red[2];
  float x = F[row * CH + j];
  float ss = x * x;
  #pragma unroll
  for (int o = 32; o; o >>= 1) ss += __shfl_xor(ss, o);
  if ((j & 63) == 0) red[j >> 6] = ss;
  __syncthreads();
  float norm = sqrtf(red[0] + red[1]);
  float xn = x / fmaxf(norm, 1e-12f);
  xs[j] = xn;
  out[row * CH + j] = xn;
  __syncthreads();
  if (j < 32) {
    float a = c1b[j];
    for (int kk = 0; kk < CH; kk++) a = fmaf(xs[kk], c1W[kk * 32 + j], a);
    h1[j] = fmaxf(a, 0.0f);
  }
  __syncthreads();
  if (j < 32) {
    float a = c2b[j];
    #pragma unroll
    for (int kk = 0; kk < 32; kk++) a = fmaf(h1[kk], c2W[kk * 32 + j], a);
    h2[j] = fmaxf(a, 0.0f);
  }
  __syncthreads();
  if (j == 0) {
    float a = c3b[0];
    #pragma unroll
    for (int kk = 0; kk < 32; kk++) a = fmaf(h2[kk], c3W[kk], a);
    out[NPTS * CH + row] = 1.0f / (1.0f + __expf(-a));
  }
}

// ---------------------------------------------------------------------------
extern "C" void kernel_launch(void* const* d_in, const int* in_sizes, int n_in,
                              void* d_out, int out_size, void* d_ws, size_t ws_size,
                              hipStream_t stream) {
  const float* refp = (const float*)d_in[0];
  const float* srcp = (const float*)d_in[1];
  const float* cf   = (const float*)d_in[2];
  const float* Win  = (const float*)d_in[3];
  const float* bin  = (const float*)d_in[4];
  const float* mlpW = (const float*)d_in[5];
  const float* mlpb = (const float*)d_in[6];
  const float* mlpg = (const float*)d_in[7];
  const float* mlpbeta = (const float*)d_in[8];
  const float* Wq = (const float*)d_in[9];
  const float* bq = (const float*)d_in[10];
  const float* Wk = (const float*)d_in[11];
  const float* bk = (const float*)d_in[12];
  const float* Wv = (const float*)d_in[13];
  const float* bv = (const float*)d_in[14];
  const float* Wo = (const float*)d_in[15];
  const float* bo = (const float*)d_in[16];
  const float* lng = (const float*)d_in[17];
  const float* lnb = (const float*)d_in[18];
  const float* c1W = (const float*)d_in[19];
  const float* c1b = (const float*)d_in[20];
  const float* c2W = (const float*)d_in[21];
  const float* c2b = (const float*)d_in[22];
  const float* c3W = (const float*)d_in[23];
  const float* c3b = (const float*)d_in[24];
  float* out = (float*)d_out;

  const size_t NC = (size_t)NPTS * CH;
  float* F = (float*)d_ws;
  float* T = F + NC;
  float* A = T + NC;
  ushort* Qb  = (ushort*)(A + NC);
  ushort* Kb  = Qb + NC;
  ushort* Vtb = Kb + NC;
  float* Opart = (float*)(Vtb + NC);

  // pick largest KV-split that fits the workspace
  const size_t base_bytes = 3 * NC * 4 + 3 * NC * 2;
  int NS = 1;
  for (int cand = 16; cand >= 2; cand >>= 1) {
    size_t need = base_bytes + (size_t)cand * (NC * 4 + NPTS * 8);
    if (need <= ws_size) { NS = cand; break; }
  }
  float* ML = Opart + (size_t)NS * NC;
  const int ntiles = NPTS / 64 / NS;

  k_embed<<<NPTS, 128, 0, stream>>>(refp, srcp, cf, Win, bin, F);
  for (int i = 0; i < 3; i++) {
    const int o2 = i * CH * CH, o1 = i * CH;
    k_row_linear_ln<false, true><<<NPTS / 4, 128, 0, stream>>>(
        F, mlpW + o2, mlpb + o1, mlpg + o1, mlpbeta + o1, nullptr, T);
    k_qkv<<<NPTS / 4, 128, 0, stream>>>(
        T, Wq + o2, bq + o1, Wk + o2, bk + o1, Wv + o2, bv + o1, Qb, Kb, Vtb);
    dim3 agrid(NPTS / 64, NS);
    k_attn_mfma<<<agrid, 256, 0, stream>>>(Qb, Kb, Vtb, refp, srcp, Opart, ML, ntiles);
    k_attn_combine<<<NPTS, 128, 0, stream>>>(Opart, ML, A, NS);
    k_row_linear_ln<true, false><<<NPTS / 4, 128, 0, stream>>>(
        A, Wo + o2, bo + o1, lng + o1, lnb + o1, T, F);
  }
  k_final<<<NPTS, 128, 0, stream>>>(F, c1W, c1b, c2W, c2b, c3W, c3b, out);
}

// Round 5
// 372.196 us; speedup vs baseline: 7.8029x; 1.2521x over previous
//
#include <hip/hip_runtime.h>
#include <math.h>

#define NPTS 6144
#define CH   128

typedef __attribute__((ext_vector_type(8))) short short8;
typedef __attribute__((ext_vector_type(4))) float f32x4;
typedef __attribute__((ext_vector_type(2))) float f32x2;
typedef __attribute__((ext_vector_type(4))) int   i32x4;
typedef __attribute__((ext_vector_type(2))) int   i32x2;

__device__ inline ushort f2bf(float f) {
  union { float f; unsigned u; } v; v.f = f;
  unsigned u = v.u;
  u += 0x7fff + ((u >> 16) & 1);   // round-to-nearest-even
  return (ushort)(u >> 16);
}

__device__ inline f32x2 splat2(float x) { return (f32x2){x, x}; }

__device__ inline float fsqrt(float x) {
  float r; asm("v_sqrt_f32 %0, %1" : "=v"(r) : "v"(x)); return r;
}
__device__ inline float fexp2(float x) {
  float r; asm("v_exp_f32 %0, %1" : "=v"(r) : "v"(x)); return r;
}

// ---------------------------------------------------------------------------
// Kernel 1: embedding  feat = [corr_feat, centered(kp)] @ W_in + b_in
// ---------------------------------------------------------------------------
__global__ __launch_bounds__(128) void k_embed(
    const float* __restrict__ refp, const float* __restrict__ srcp,
    const float* __restrict__ cf, const float* __restrict__ Win,
    const float* __restrict__ bin, float* __restrict__ out) {
  const int row = blockIdx.x, j = threadIdx.x;
  __shared__ float inb[12];
  __shared__ float mkp;
  if (j < 6)       inb[j] = cf[row * 6 + j];
  else if (j < 9)  inb[j] = refp[row * 3 + (j - 6)];
  else if (j < 12) inb[j] = srcp[row * 3 + (j - 9)];
  __syncthreads();
  if (j == 0) {
    float s = inb[6] + inb[7] + inb[8] + inb[9] + inb[10] + inb[11];
    mkp = s * (1.0f / 6.0f);
  }
  __syncthreads();
  float acc = bin[j];
  #pragma unroll
  for (int kk = 0; kk < 12; kk++) {
    float x = inb[kk] - (kk >= 6 ? mkp : 0.0f);
    acc = fmaf(x, Win[kk * CH + j], acc);
  }
  out[row * CH + j] = acc;
}

// ---------------------------------------------------------------------------
// Kernel 2/5: per-row linear + (residual) + LayerNorm + (leaky relu)
// ---------------------------------------------------------------------------
template <bool RESID, bool LEAKY>
__global__ __launch_bounds__(128) void k_row_linear_ln(
    const float* __restrict__ X, const float* __restrict__ W,
    const float* __restrict__ b, const float* __restrict__ g,
    const float* __restrict__ beta, const float* __restrict__ res,
    float* __restrict__ out) {
  const int j = threadIdx.x;
  const int r0 = blockIdx.x * 4;
  __shared__ float xs[4][CH];
  __shared__ float red[2][4];
  #pragma unroll
  for (int r = 0; r < 4; r++) xs[r][j] = X[(r0 + r) * CH + j];
  __syncthreads();

  float acc[4];
  const float bj = b[j];
  #pragma unroll
  for (int r = 0; r < 4; r++) acc[r] = bj;
  for (int kk = 0; kk < CH; kk++) {
    float w = W[kk * CH + j];
    #pragma unroll
    for (int r = 0; r < 4; r++) acc[r] = fmaf(xs[r][kk], w, acc[r]);
  }
  if (RESID) {
    #pragma unroll
    for (int r = 0; r < 4; r++) acc[r] += res[(r0 + r) * CH + j];
  }

  const int wv = j >> 6, ln = j & 63;
  float sum[4];
  #pragma unroll
  for (int r = 0; r < 4; r++) sum[r] = acc[r];
  #pragma unroll
  for (int o = 32; o; o >>= 1) {
    #pragma unroll
    for (int r = 0; r < 4; r++) sum[r] += __shfl_xor(sum[r], o);
  }
  if (ln == 0) {
    #pragma unroll
    for (int r = 0; r < 4; r++) red[wv][r] = sum[r];
  }
  __syncthreads();
  float mean[4], dv[4];
  #pragma unroll
  for (int r = 0; r < 4; r++) {
    mean[r] = (red[0][r] + red[1][r]) * (1.0f / 128.0f);
    dv[r] = acc[r] - mean[r];
    sum[r] = dv[r] * dv[r];
  }
  #pragma unroll
  for (int o = 32; o; o >>= 1) {
    #pragma unroll
    for (int r = 0; r < 4; r++) sum[r] += __shfl_xor(sum[r], o);
  }
  __syncthreads();
  if (ln == 0) {
    #pragma unroll
    for (int r = 0; r < 4; r++) red[wv][r] = sum[r];
  }
  __syncthreads();
  const float gj = g[j], betaj = beta[j];
  #pragma unroll
  for (int r = 0; r < 4; r++) {
    float var = (red[0][r] + red[1][r]) * (1.0f / 128.0f);
    float y = dv[r] * rsqrtf(var + 1e-5f) * gj + betaj;
    if (LEAKY) y = (y > 0.0f) ? y : 0.1f * y;
    out[(r0 + r) * CH + j] = y;
  }
}

// ---------------------------------------------------------------------------
// Kernel 3: fused QKV projection -> bf16 Q (pre-scaled by log2e/sqrt(C)), K
// row-major; V transposed bf16.
// ---------------------------------------------------------------------------
__global__ __launch_bounds__(128) void k_qkv(
    const float* __restrict__ X,
    const float* __restrict__ Wq, const float* __restrict__ bq,
    const float* __restrict__ Wk, const float* __restrict__ bk,
    const float* __restrict__ Wv, const float* __restrict__ bv,
    ushort* __restrict__ Q, ushort* __restrict__ K, ushort* __restrict__ Vt) {
  const int j = threadIdx.x;
  const int r0 = blockIdx.x * 4;
  __shared__ float xs[4][CH];
  #pragma unroll
  for (int r = 0; r < 4; r++) xs[r][j] = X[(r0 + r) * CH + j];
  __syncthreads();
  float aq[4], ak[4], av[4];
  const float bqj = bq[j], bkj = bk[j], bvj = bv[j];
  #pragma unroll
  for (int r = 0; r < 4; r++) { aq[r] = bqj; ak[r] = bkj; av[r] = bvj; }
  for (int kk = 0; kk < CH; kk++) {
    float wq = Wq[kk * CH + j], wk = Wk[kk * CH + j], wv = Wv[kk * CH + j];
    #pragma unroll
    for (int r = 0; r < 4; r++) {
      float x = xs[r][kk];
      aq[r] = fmaf(x, wq, aq[r]);
      ak[r] = fmaf(x, wk, ak[r]);
      av[r] = fmaf(x, wv, av[r]);
    }
  }
  // 1/sqrt(128) * log2(e): softmax runs in log2 domain
  const float scale = 0.12751879524143007f;
  #pragma unroll
  for (int r = 0; r < 4; r++) {
    Q[(r0 + r) * CH + j] = f2bf(aq[r] * scale);
    K[(r0 + r) * CH + j] = f2bf(ak[r]);
  }
  ushort4 vp;
  vp.x = f2bf(av[0]); vp.y = f2bf(av[1]); vp.z = f2bf(av[2]); vp.w = f2bf(av[3]);
  *(ushort4*)(Vt + (size_t)j * NPTS + r0) = vp;
}

// ---------------------------------------------------------------------------
// Kernel 4: MFMA flash attention, KV-split, swapped-QK^T (S^T) so each lane
// owns one q-row; PV uses a key-permuted V^T A-fragment so the P operand is
// the lane's own registers. K tile XOR-swizzled (row&7)<<4 to kill the
// 8-way bank conflict on the QK A-frag ds_read_b128.
// geo: (dr-ds)^2 = d2r + d2s - 2*sqrt(d2r*d2s)  (one raw v_sqrt per pair).
// Softmax in log2 domain with defer-rescale (THR=11 in log2 units).
// ---------------------------------------------------------------------------
__global__ __launch_bounds__(256) void k_attn_mfma(
    const ushort* __restrict__ Q, const ushort* __restrict__ K,
    const ushort* __restrict__ Vt,
    const float* __restrict__ refp, const float* __restrict__ srcp,
    float* __restrict__ Opart, float* __restrict__ ML, int ntiles) {
  const int tid = threadIdx.x;
  const int w = tid >> 6, ln = tid & 63;
  const int l15 = ln & 15, g = ln >> 4;
  const int row0 = blockIdx.x * 64;
  const int seg = blockIdx.y;
  const int t0 = seg * ntiles;

  __shared__ ushort Ks[64 * 128];   // K tile, 256B/row, XOR-swizzled
  __shared__ ushort Vts[128][72];   // V^T tile [ch][key], 144B row stride
  __shared__ float cs2[6][64];      // tile coords, coord-major

  // Q B-fragment: lane (g,l15) provides B[k=8g+i][col=l15]
  short8 qf[4];
  {
    const ushort* qp = Q + (size_t)(row0 + 16 * w + l15) * CH + 8 * g;
    #pragma unroll
    for (int ks = 0; ks < 4; ks++) qf[ks] = *(const short8*)(qp + 32 * ks);
  }
  const int qrow = row0 + 16 * w + l15;
  const float rq0 = refp[qrow * 3], rq1 = refp[qrow * 3 + 1], rq2 = refp[qrow * 3 + 2];
  const float sq0 = srcp[qrow * 3], sq1 = srcp[qrow * 3 + 1], sq2 = srcp[qrow * 3 + 2];

  f32x4 oacc[8];
  #pragma unroll
  for (int n = 0; n < 8; n++) oacc[n] = (f32x4){0.f, 0.f, 0.f, 0.f};
  float m = -1e30f, l = 0.0f;
  const float invs2 = 1.0f / (0.3f * 0.3f);

  for (int tt = 0; tt < ntiles; tt++) {
    const int t = t0 + tt;
    __syncthreads();
    #pragma unroll
    for (int s = 0; s < 4; s++) {             // K tile: 64x128 bf16, swizzled
      int idx = tid + 256 * s;
      int row = idx >> 4, c8 = idx & 15;
      char* dst = (char*)Ks + row * 256 + ((c8 * 16) ^ ((row & 7) << 4));
      *(short8*)dst = *(const short8*)(K + (size_t)(t * 64 + row) * CH + c8 * 8);
    }
    #pragma unroll
    for (int s = 0; s < 4; s++) {             // Vt tile: 128x64 bf16
      int idx = tid + 256 * s;
      int c = idx >> 3, j8 = idx & 7;
      *(short8*)&Vts[c][j8 * 8] =
          *(const short8*)(Vt + (size_t)c * NPTS + t * 64 + j8 * 8);
    }
    if (tid < 64) {
      int gj = t * 64 + tid;
      cs2[0][tid] = refp[gj * 3];     cs2[1][tid] = refp[gj * 3 + 1];
      cs2[2][tid] = refp[gj * 3 + 2]; cs2[3][tid] = srcp[gj * 3];
      cs2[4][tid] = srcp[gj * 3 + 1]; cs2[5][tid] = srcp[gj * 3 + 2];
    }
    __syncthreads();

    // ---- S^T = K @ Q^T : lane holds S[q=l15][key=16nb+4g+r] ----
    f32x4 acc[4];
    #pragma unroll
    for (int nb = 0; nb < 4; nb++) acc[nb] = (f32x4){0.f, 0.f, 0.f, 0.f};
    __builtin_amdgcn_s_setprio(1);
    #pragma unroll
    for (int ks = 0; ks < 4; ks++) {
      #pragma unroll
      for (int nb = 0; nb < 4; nb++) {
        int krow = 16 * nb + l15;
        const char* src = (const char*)Ks + krow * 256 +
                          ((64 * ks + 16 * g) ^ ((krow & 7) << 4));
        short8 af = *(const short8*)src;
        acc[nb] = __builtin_amdgcn_mfma_f32_16x16x32_bf16(af, qf[ks], acc[nb], 0, 0, 0);
      }
    }
    __builtin_amdgcn_s_setprio(0);

    // ---- geo(q, key) * S  (log2-domain logits) ----
    float plog[4][4];
    #pragma unroll
    for (int nb = 0; nb < 4; nb++) {
      const int kb = 16 * nb + 4 * g;
      #pragma unroll
      for (int pp = 0; pp < 2; pp++) {
        const int k2 = kb + 2 * pp;
        f32x2 cx = *(const f32x2*)&cs2[0][k2];
        f32x2 cy = *(const f32x2*)&cs2[1][k2];
        f32x2 cz = *(const f32x2*)&cs2[2][k2];
        f32x2 dx = splat2(rq0) - cx, dy = splat2(rq1) - cy, dz = splat2(rq2) - cz;
        f32x2 d2r = dx * dx + dy * dy + dz * dz;
        cx = *(const f32x2*)&cs2[3][k2];
        cy = *(const f32x2*)&cs2[4][k2];
        cz = *(const f32x2*)&cs2[5][k2];
        dx = splat2(sq0) - cx; dy = splat2(sq1) - cy; dz = splat2(sq2) - cz;
        f32x2 d2s = dx * dx + dy * dy + dz * dz;
        f32x2 prod = d2r * d2s;
        f32x2 sum2 = d2r + d2s;
        float s0 = fsqrt(prod[0]), s1 = fsqrt(prod[1]);
        float dd20 = fmaf(-2.0f, s0, sum2[0]);   // (dr - ds)^2
        float dd21 = fmaf(-2.0f, s1, sum2[1]);
        float gg0 = fmaxf(fmaf(dd20, -invs2, 1.0f), 0.0f);
        float gg1 = fmaxf(fmaf(dd21, -invs2, 1.0f), 0.0f);
        plog[nb][2 * pp]     = gg0 * acc[nb][2 * pp];
        plog[nb][2 * pp + 1] = gg1 * acc[nb][2 * pp + 1];
      }
    }

    // ---- online softmax (log2 domain, defer-rescale) ----
    float tm = fmaxf(fmaxf(plog[0][0], plog[0][1]), fmaxf(plog[0][2], plog[0][3]));
    #pragma unroll
    for (int nb = 1; nb < 4; nb++) {
      float t2 = fmaxf(fmaxf(plog[nb][0], plog[nb][1]),
                       fmaxf(plog[nb][2], plog[nb][3]));
      tm = fmaxf(tm, t2);
    }
    tm = fmaxf(tm, __shfl_xor(tm, 16));
    tm = fmaxf(tm, __shfl_xor(tm, 32));
    if (__any(tm > m + 11.0f)) {    // defer-rescale: p bounded by 2^11
      float nm = fmaxf(m, tm);
      float rsc = fexp2(m - nm);
      l *= rsc;
      #pragma unroll
      for (int n = 0; n < 8; n++) oacc[n] *= rsc;
      m = nm;
    }
    float psum = 0.0f;
    #pragma unroll
    for (int nb = 0; nb < 4; nb++)
      #pragma unroll
      for (int r = 0; r < 4; r++) {
        float p = fexp2(plog[nb][r] - m);
        plog[nb][r] = p;
        psum += p;
      }
    psum += __shfl_xor(psum, 16);
    psum += __shfl_xor(psum, 32);
    l += psum;

    // ---- pack P to bf16 pairs (lane-local PV B-fragment) ----
    unsigned pk[4][2];
    #pragma unroll
    for (int nb = 0; nb < 4; nb++) {
      asm("v_cvt_pk_bf16_f32 %0, %1, %2"
          : "=v"(pk[nb][0]) : "v"(plog[nb][0]), "v"(plog[nb][1]));
      asm("v_cvt_pk_bf16_f32 %0, %1, %2"
          : "=v"(pk[nb][1]) : "v"(plog[nb][2]), "v"(plog[nb][3]));
    }

    // ---- O^T += V^T(permuted) @ P^T ----
    union U16 { i32x4 i; short8 s; };
    __builtin_amdgcn_s_setprio(1);
    #pragma unroll
    for (int ks2 = 0; ks2 < 2; ks2++) {
      U16 b;
      b.i[0] = (int)pk[2 * ks2][0];
      b.i[1] = (int)pk[2 * ks2][1];
      b.i[2] = (int)pk[2 * ks2 + 1][0];
      b.i[3] = (int)pk[2 * ks2 + 1][1];
      #pragma unroll
      for (int nb2 = 0; nb2 < 8; nb2++) {
        const ushort* vp2 = &Vts[16 * nb2 + l15][32 * ks2 + 4 * g];
        i32x2 a0 = *(const i32x2*)vp2;
        i32x2 a1 = *(const i32x2*)(vp2 + 16);
        U16 a;
        a.i[0] = a0[0]; a.i[1] = a0[1]; a.i[2] = a1[0]; a.i[3] = a1[1];
        oacc[nb2] = __builtin_amdgcn_mfma_f32_16x16x32_bf16(a.s, b.s, oacc[nb2], 0, 0, 0);
      }
    }
    __builtin_amdgcn_s_setprio(0);
  }

  // write unnormalized partial + (m, l);  lane holds O[q=l15][d=16nb2+4g+r]
  {
    float* op = Opart + ((size_t)seg * NPTS + qrow) * CH;
    #pragma unroll
    for (int nb2 = 0; nb2 < 8; nb2++)
      *(f32x4*)(op + 16 * nb2 + 4 * g) = oacc[nb2];
    if (g == 0) {
      ML[((size_t)seg * NPTS + qrow) * 2]     = m;
      ML[((size_t)seg * NPTS + qrow) * 2 + 1] = l;
    }
  }
}

// ---------------------------------------------------------------------------
// Kernel 4b: combine the NS partials (vectorized: 8 rows/block, float4/lane).
// ---------------------------------------------------------------------------
__global__ __launch_bounds__(256) void k_attn_combine(
    const float* __restrict__ Opart, const float* __restrict__ ML,
    float* __restrict__ out, int NS) {
  const int tid = threadIdx.x;
  const int row = blockIdx.x * 8 + (tid >> 5);
  const int c4 = (tid & 31) * 4;
  float M = -1e30f;
  for (int s = 0; s < NS; s++)
    M = fmaxf(M, ML[((size_t)s * NPTS + row) * 2]);
  float L = 0.0f;
  f32x4 acc = (f32x4){0.f, 0.f, 0.f, 0.f};
  for (int s = 0; s < NS; s++) {
    float ms = ML[((size_t)s * NPTS + row) * 2];
    float ls = ML[((size_t)s * NPTS + row) * 2 + 1];
    float wsc = fexp2(ms - M);
    L += wsc * ls;
    f32x4 o = *(const f32x4*)&Opart[((size_t)s * NPTS + row) * CH + c4];
    acc[0] = fmaf(wsc, o[0], acc[0]);
    acc[1] = fmaf(wsc, o[1], acc[1]);
    acc[2] = fmaf(wsc, o[2], acc[2]);
    acc[3] = fmaf(wsc, o[3], acc[3]);
  }
  float inv = 1.0f / L;
  f32x4 r = acc * (f32x4){inv, inv, inv, inv};
  *(f32x4*)&out[(size_t)row * CH + c4] = r;
}

// ---------------------------------------------------------------------------
// Kernel 6: final row normalize + classifier MLP + sigmoid
// ---------------------------------------------------------------------------
__global__ __launch_bounds__(128) void k_final(
    const float* __restrict__ F,
    const float* __restrict__ c1W, const float* __restrict__ c1b,
    const float* __restrict__ c2W, const float* __restrict__ c2b,
    const float* __restrict__ c3W, const float* __restrict__ c3b,
    float* __restrict__ out) {
  const int row = blockIdx.x, j = threadIdx.x;
  __shared__ float xs[CH];
  __shared__ float h1[32];
  __shared__ float h2[32];
  __shared__ float red[2];
  float x = F[row * CH + j];
  float ss = x * x;
  #pragma unroll
  for (int o = 32; o; o >>= 1) ss += __shfl_xor(ss, o);
  if ((j & 63) == 0) red[j >> 6] = ss;
  __syncthreads();
  float norm = sqrtf(red[0] + red[1]);
  float xn = x / fmaxf(norm, 1e-12f);
  xs[j] = xn;
  out[row * CH + j] = xn;
  __syncthreads();
  if (j < 32) {
    float a = c1b[j];
    for (int kk = 0; kk < CH; kk++) a = fmaf(xs[kk], c1W[kk * 32 + j], a);
    h1[j] = fmaxf(a, 0.0f);
  }
  __syncthreads();
  if (j < 32) {
    float a = c2b[j];
    #pragma unroll
    for (int kk = 0; kk < 32; kk++) a = fmaf(h1[kk], c2W[kk * 32 + j], a);
    h2[j] = fmaxf(a, 0.0f);
  }
  __syncthreads();
  if (j == 0) {
    float a = c3b[0];
    #pragma unroll
    for (int kk = 0; kk < 32; kk++) a = fmaf(h2[kk], c3W[kk], a);
    out[NPTS * CH + row] = 1.0f / (1.0f + __expf(-a));
  }
}

// ---------------------------------------------------------------------------
extern "C" void kernel_launch(void* const* d_in, const int* in_sizes, int n_in,
                              void* d_out, int out_size, void* d_ws, size_t ws_size,
                              hipStream_t stream) {
  const float* refp = (const float*)d_in[0];
  const float* srcp = (const float*)d_in[1];
  const float* cf   = (const float*)d_in[2];
  const float* Win  = (const float*)d_in[3];
  const float* bin  = (const float*)d_in[4];
  const float* mlpW = (const float*)d_in[5];
  const float* mlpb = (const float*)d_in[6];
  const float* mlpg = (const float*)d_in[7];
  const float* mlpbeta = (const float*)d_in[8];
  const float* Wq = (const float*)d_in[9];
  const float* bq = (const float*)d_in[10];
  const float* Wk = (const float*)d_in[11];
  const float* bk = (const float*)d_in[12];
  const float* Wv = (const float*)d_in[13];
  const float* bv = (const float*)d_in[14];
  const float* Wo = (const float*)d_in[15];
  const float* bo = (const float*)d_in[16];
  const float* lng = (const float*)d_in[17];
  const float* lnb = (const float*)d_in[18];
  const float* c1W = (const float*)d_in[19];
  const float* c1b = (const float*)d_in[20];
  const float* c2W = (const float*)d_in[21];
  const float* c2b = (const float*)d_in[22];
  const float* c3W = (const float*)d_in[23];
  const float* c3b = (const float*)d_in[24];
  float* out = (float*)d_out;

  const size_t NC = (size_t)NPTS * CH;
  float* F = (float*)d_ws;
  float* T = F + NC;
  float* A = T + NC;
  ushort* Qb  = (ushort*)(A + NC);
  ushort* Kb  = Qb + NC;
  ushort* Vtb = Kb + NC;
  float* Opart = (float*)(Vtb + NC);

  // pick largest KV-split that fits the workspace
  const size_t base_bytes = 3 * NC * 4 + 3 * NC * 2;
  int NS = 1;
  for (int cand = 16; cand >= 2; cand >>= 1) {
    size_t need = base_bytes + (size_t)cand * (NC * 4 + NPTS * 8);
    if (need <= ws_size) { NS = cand; break; }
  }
  float* ML = Opart + (size_t)NS * NC;
  const int ntiles = NPTS / 64 / NS;

  k_embed<<<NPTS, 128, 0, stream>>>(refp, srcp, cf, Win, bin, F);
  for (int i = 0; i < 3; i++) {
    const int o2 = i * CH * CH, o1 = i * CH;
    k_row_linear_ln<false, true><<<NPTS / 4, 128, 0, stream>>>(
        F, mlpW + o2, mlpb + o1, mlpg + o1, mlpbeta + o1, nullptr, T);
    k_qkv<<<NPTS / 4, 128, 0, stream>>>(
        T, Wq + o2, bq + o1, Wk + o2, bk + o1, Wv + o2, bv + o1, Qb, Kb, Vtb);
    dim3 agrid(NPTS / 64, NS);
    k_attn_mfma<<<agrid, 256, 0, stream>>>(Qb, Kb, Vtb, refp, srcp, Opart, ML, ntiles);
    k_attn_combine<<<NPTS / 8, 256, 0, stream>>>(Opart, ML, A, NS);
    k_row_linear_ln<true, false><<<NPTS / 4, 128, 0, stream>>>(
        A, Wo + o2, bo + o1, lng + o1, lnb + o1, T, F);
  }
  k_final<<<NPTS, 128, 0, stream>>>(F, c1W, c1b, c2W, c2b, c3W, c3b, out);
}

// Round 6
// 352.966 us; speedup vs baseline: 8.2280x; 1.0545x over previous
//
#include <hip/hip_runtime.h>
#include <math.h>

#define NPTS 6144
#define CH   128

typedef __attribute__((ext_vector_type(8))) short short8;
typedef __attribute__((ext_vector_type(4))) float f32x4;
typedef __attribute__((ext_vector_type(2))) float f32x2;
typedef __attribute__((ext_vector_type(4))) int   i32x4;
typedef __attribute__((ext_vector_type(2))) int   i32x2;

__device__ inline ushort f2bf(float f) {
  union { float f; unsigned u; } v; v.f = f;
  unsigned u = v.u;
  u += 0x7fff + ((u >> 16) & 1);   // round-to-nearest-even
  return (ushort)(u >> 16);
}

__device__ inline f32x2 splat2(float x) { return (f32x2){x, x}; }

__device__ inline float fsqrt(float x) {
  float r; asm("v_sqrt_f32 %0, %1" : "=v"(r) : "v"(x)); return r;
}
__device__ inline float fexp2(float x) {
  float r; asm("v_exp_f32 %0, %1" : "=v"(r) : "v"(x)); return r;
}

// ---------------------------------------------------------------------------
// Kernel 1: embedding  feat = [corr_feat, centered(kp)] @ W_in + b_in
// ---------------------------------------------------------------------------
__global__ __launch_bounds__(128) void k_embed(
    const float* __restrict__ refp, const float* __restrict__ srcp,
    const float* __restrict__ cf, const float* __restrict__ Win,
    const float* __restrict__ bin, float* __restrict__ out) {
  const int row = blockIdx.x, j = threadIdx.x;
  __shared__ float inb[12];
  __shared__ float mkp;
  if (j < 6)       inb[j] = cf[row * 6 + j];
  else if (j < 9)  inb[j] = refp[row * 3 + (j - 6)];
  else if (j < 12) inb[j] = srcp[row * 3 + (j - 9)];
  __syncthreads();
  if (j == 0) {
    float s = inb[6] + inb[7] + inb[8] + inb[9] + inb[10] + inb[11];
    mkp = s * (1.0f / 6.0f);
  }
  __syncthreads();
  float acc = bin[j];
  #pragma unroll
  for (int kk = 0; kk < 12; kk++) {
    float x = inb[kk] - (kk >= 6 ? mkp : 0.0f);
    acc = fmaf(x, Win[kk * CH + j], acc);
  }
  out[row * CH + j] = acc;
}

// ---------------------------------------------------------------------------
// Kernel 2/5: per-row linear + (residual) + LayerNorm + (leaky relu)
// ---------------------------------------------------------------------------
template <bool RESID, bool LEAKY>
__global__ __launch_bounds__(128) void k_row_linear_ln(
    const float* __restrict__ X, const float* __restrict__ W,
    const float* __restrict__ b, const float* __restrict__ g,
    const float* __restrict__ beta, const float* __restrict__ res,
    float* __restrict__ out) {
  const int j = threadIdx.x;
  const int r0 = blockIdx.x * 4;
  __shared__ float xs[4][CH];
  __shared__ float red[2][4];
  #pragma unroll
  for (int r = 0; r < 4; r++) xs[r][j] = X[(r0 + r) * CH + j];
  __syncthreads();

  float acc[4];
  const float bj = b[j];
  #pragma unroll
  for (int r = 0; r < 4; r++) acc[r] = bj;
  for (int kk = 0; kk < CH; kk++) {
    float w = W[kk * CH + j];
    #pragma unroll
    for (int r = 0; r < 4; r++) acc[r] = fmaf(xs[r][kk], w, acc[r]);
  }
  if (RESID) {
    #pragma unroll
    for (int r = 0; r < 4; r++) acc[r] += res[(r0 + r) * CH + j];
  }

  const int wv = j >> 6, ln = j & 63;
  float sum[4];
  #pragma unroll
  for (int r = 0; r < 4; r++) sum[r] = acc[r];
  #pragma unroll
  for (int o = 32; o; o >>= 1) {
    #pragma unroll
    for (int r = 0; r < 4; r++) sum[r] += __shfl_xor(sum[r], o);
  }
  if (ln == 0) {
    #pragma unroll
    for (int r = 0; r < 4; r++) red[wv][r] = sum[r];
  }
  __syncthreads();
  float mean[4], dv[4];
  #pragma unroll
  for (int r = 0; r < 4; r++) {
    mean[r] = (red[0][r] + red[1][r]) * (1.0f / 128.0f);
    dv[r] = acc[r] - mean[r];
    sum[r] = dv[r] * dv[r];
  }
  #pragma unroll
  for (int o = 32; o; o >>= 1) {
    #pragma unroll
    for (int r = 0; r < 4; r++) sum[r] += __shfl_xor(sum[r], o);
  }
  __syncthreads();
  if (ln == 0) {
    #pragma unroll
    for (int r = 0; r < 4; r++) red[wv][r] = sum[r];
  }
  __syncthreads();
  const float gj = g[j], betaj = beta[j];
  #pragma unroll
  for (int r = 0; r < 4; r++) {
    float var = (red[0][r] + red[1][r]) * (1.0f / 128.0f);
    float y = dv[r] * rsqrtf(var + 1e-5f) * gj + betaj;
    if (LEAKY) y = (y > 0.0f) ? y : 0.1f * y;
    out[(r0 + r) * CH + j] = y;
  }
}

// ---------------------------------------------------------------------------
// Kernel 3: fused QKV projection -> bf16 Q (pre-scaled by log2e/sqrt(C)), K
// row-major; V transposed bf16.
// ---------------------------------------------------------------------------
__global__ __launch_bounds__(128) void k_qkv(
    const float* __restrict__ X,
    const float* __restrict__ Wq, const float* __restrict__ bq,
    const float* __restrict__ Wk, const float* __restrict__ bk,
    const float* __restrict__ Wv, const float* __restrict__ bv,
    ushort* __restrict__ Q, ushort* __restrict__ K, ushort* __restrict__ Vt) {
  const int j = threadIdx.x;
  const int r0 = blockIdx.x * 4;
  __shared__ float xs[4][CH];
  #pragma unroll
  for (int r = 0; r < 4; r++) xs[r][j] = X[(r0 + r) * CH + j];
  __syncthreads();
  float aq[4], ak[4], av[4];
  const float bqj = bq[j], bkj = bk[j], bvj = bv[j];
  #pragma unroll
  for (int r = 0; r < 4; r++) { aq[r] = bqj; ak[r] = bkj; av[r] = bvj; }
  for (int kk = 0; kk < CH; kk++) {
    float wq = Wq[kk * CH + j], wk = Wk[kk * CH + j], wv = Wv[kk * CH + j];
    #pragma unroll
    for (int r = 0; r < 4; r++) {
      float x = xs[r][kk];
      aq[r] = fmaf(x, wq, aq[r]);
      ak[r] = fmaf(x, wk, ak[r]);
      av[r] = fmaf(x, wv, av[r]);
    }
  }
  // 1/sqrt(128) * log2(e): softmax runs in log2 domain
  const float scale = 0.12751879524143007f;
  #pragma unroll
  for (int r = 0; r < 4; r++) {
    Q[(r0 + r) * CH + j] = f2bf(aq[r] * scale);
    K[(r0 + r) * CH + j] = f2bf(ak[r]);
  }
  ushort4 vp;
  vp.x = f2bf(av[0]); vp.y = f2bf(av[1]); vp.z = f2bf(av[2]); vp.w = f2bf(av[3]);
  *(ushort4*)(Vt + (size_t)j * NPTS + r0) = vp;
}

// ---------------------------------------------------------------------------
// Kernel 4: MFMA flash attention, KV-split.
// 512 threads = 8 waves; block owns 128 q-rows (16/wave), 64-key tiles.
// Double-buffered LDS, async-stage (issue loads early, ds_write after
// barrier) -> ONE barrier per tile, global latency hidden under compute.
// V tile stored pre-permuted so PV A-frag is a single ds_read_b128.
// ---------------------------------------------------------------------------
__global__ __launch_bounds__(512, 4) void k_attn_mfma(
    const ushort* __restrict__ Q, const ushort* __restrict__ K,
    const ushort* __restrict__ Vt,
    const float* __restrict__ refp, const float* __restrict__ srcp,
    float* __restrict__ Opart, float* __restrict__ ML, int ntiles) {
  const int tid = threadIdx.x;
  const int w = tid >> 6, ln = tid & 63;
  const int l15 = ln & 15, g = ln >> 4;
  const int row0 = blockIdx.x * 128;
  const int seg = blockIdx.y;
  const int t0 = seg * ntiles;

  __shared__ ushort Ks[2][64][136];   // K tile [key][ch], 272B row stride
  __shared__ ushort Vs[2][128][72];   // permuted V^T tile [ch][slot]
  __shared__ float cs2[2][6][64];     // tile coords, coord-major

  // staging geometry (2 chunks each of K and V per thread)
  const int krow0 = tid >> 4;        // 0..31
  const int kc8   = tid & 15;
  const int vch0  = tid >> 3;        // 0..63
  const int vj8   = tid & 7;
  const int vbase = 32 * (vj8 >> 2) + 4 * (vj8 & 3);

  short8 kreg0, kreg1;
  i32x2 va0, vb0, va1, vb1;
  float cr[6];

  auto issue = [&](int t) {
    const ushort* kp = K + (size_t)(t * 64) * CH + kc8 * 8;
    kreg0 = *(const short8*)(kp + (size_t)krow0 * CH);
    kreg1 = *(const short8*)(kp + (size_t)(krow0 + 32) * CH);
    const ushort* vp0 = Vt + (size_t)vch0 * NPTS + t * 64 + vbase;
    const ushort* vp1 = vp0 + (size_t)64 * NPTS;
    va0 = *(const i32x2*)vp0;  vb0 = *(const i32x2*)(vp0 + 16);
    va1 = *(const i32x2*)vp1;  vb1 = *(const i32x2*)(vp1 + 16);
    if (tid < 64) {
      int gj = t * 64 + tid;
      cr[0] = refp[gj * 3]; cr[1] = refp[gj * 3 + 1]; cr[2] = refp[gj * 3 + 2];
      cr[3] = srcp[gj * 3]; cr[4] = srcp[gj * 3 + 1]; cr[5] = srcp[gj * 3 + 2];
    }
    __builtin_amdgcn_sched_barrier(0);
  };

  auto commit = [&](int cb) {
    *(short8*)&Ks[cb][krow0][kc8 * 8] = kreg0;
    *(short8*)&Ks[cb][krow0 + 32][kc8 * 8] = kreg1;
    union U16 { i32x4 i; short8 s; } u0, u1;
    u0.i[0] = va0[0]; u0.i[1] = va0[1]; u0.i[2] = vb0[0]; u0.i[3] = vb0[1];
    u1.i[0] = va1[0]; u1.i[1] = va1[1]; u1.i[2] = vb1[0]; u1.i[3] = vb1[1];
    *(short8*)&Vs[cb][vch0][vj8 * 8] = u0.s;
    *(short8*)&Vs[cb][vch0 + 64][vj8 * 8] = u1.s;
    if (tid < 64) {
      #pragma unroll
      for (int d = 0; d < 6; d++) cs2[cb][d][tid] = cr[d];
    }
  };

  // Q B-fragment: lane (g,l15) provides B[k=8g+i][col=l15]
  short8 qf[4];
  {
    const ushort* qp = Q + (size_t)(row0 + 16 * w + l15) * CH + 8 * g;
    #pragma unroll
    for (int ks = 0; ks < 4; ks++) qf[ks] = *(const short8*)(qp + 32 * ks);
  }
  const int qrow = row0 + 16 * w + l15;
  const float rq0 = refp[qrow * 3], rq1 = refp[qrow * 3 + 1], rq2 = refp[qrow * 3 + 2];
  const float sq0 = srcp[qrow * 3], sq1 = srcp[qrow * 3 + 1], sq2 = srcp[qrow * 3 + 2];

  f32x4 oacc[8];
  #pragma unroll
  for (int n = 0; n < 8; n++) oacc[n] = (f32x4){0.f, 0.f, 0.f, 0.f};
  float m = -1e30f, l = 0.0f;
  const float invs2 = 1.0f / (0.3f * 0.3f);

  issue(t0);
  int cb = 0;
  for (int tt = 0; tt < ntiles; tt++) {
    commit(cb);
    __syncthreads();
    if (tt + 1 < ntiles) issue(t0 + tt + 1);

    // ---- S^T = K @ Q^T : lane holds S[q=l15][key=16nb+4g+r] ----
    f32x4 acc[4];
    #pragma unroll
    for (int nb = 0; nb < 4; nb++) acc[nb] = (f32x4){0.f, 0.f, 0.f, 0.f};
    __builtin_amdgcn_s_setprio(1);
    #pragma unroll
    for (int ks = 0; ks < 4; ks++) {
      #pragma unroll
      for (int nb = 0; nb < 4; nb++) {
        short8 af = *(const short8*)&Ks[cb][16 * nb + l15][32 * ks + 8 * g];
        acc[nb] = __builtin_amdgcn_mfma_f32_16x16x32_bf16(af, qf[ks], acc[nb], 0, 0, 0);
      }
    }
    __builtin_amdgcn_s_setprio(0);

    // ---- geo(q, key) * S  (log2-domain logits) ----
    float plog[4][4];
    #pragma unroll
    for (int nb = 0; nb < 4; nb++) {
      const int kb = 16 * nb + 4 * g;
      #pragma unroll
      for (int pp = 0; pp < 2; pp++) {
        const int k2 = kb + 2 * pp;
        f32x2 cx = *(const f32x2*)&cs2[cb][0][k2];
        f32x2 cy = *(const f32x2*)&cs2[cb][1][k2];
        f32x2 cz = *(const f32x2*)&cs2[cb][2][k2];
        f32x2 dx = splat2(rq0) - cx, dy = splat2(rq1) - cy, dz = splat2(rq2) - cz;
        f32x2 d2r = dx * dx + dy * dy + dz * dz;
        cx = *(const f32x2*)&cs2[cb][3][k2];
        cy = *(const f32x2*)&cs2[cb][4][k2];
        cz = *(const f32x2*)&cs2[cb][5][k2];
        dx = splat2(sq0) - cx; dy = splat2(sq1) - cy; dz = splat2(sq2) - cz;
        f32x2 d2s = dx * dx + dy * dy + dz * dz;
        f32x2 prod = d2r * d2s;
        f32x2 sum2 = d2r + d2s;
        float s0 = fsqrt(prod[0]), s1 = fsqrt(prod[1]);
        float dd20 = fmaf(-2.0f, s0, sum2[0]);   // (dr - ds)^2
        float dd21 = fmaf(-2.0f, s1, sum2[1]);
        float gg0 = fmaxf(fmaf(dd20, -invs2, 1.0f), 0.0f);
        float gg1 = fmaxf(fmaf(dd21, -invs2, 1.0f), 0.0f);
        plog[nb][2 * pp]     = gg0 * acc[nb][2 * pp];
        plog[nb][2 * pp + 1] = gg1 * acc[nb][2 * pp + 1];
      }
    }

    // ---- online softmax (log2 domain, defer-rescale) ----
    float tm = fmaxf(fmaxf(plog[0][0], plog[0][1]), fmaxf(plog[0][2], plog[0][3]));
    #pragma unroll
    for (int nb = 1; nb < 4; nb++) {
      float t2 = fmaxf(fmaxf(plog[nb][0], plog[nb][1]),
                       fmaxf(plog[nb][2], plog[nb][3]));
      tm = fmaxf(tm, t2);
    }
    tm = fmaxf(tm, __shfl_xor(tm, 16));
    tm = fmaxf(tm, __shfl_xor(tm, 32));
    if (__any(tm > m + 11.0f)) {    // defer-rescale: p bounded by 2^11
      float nm = fmaxf(m, tm);
      float rsc = fexp2(m - nm);
      l *= rsc;
      #pragma unroll
      for (int n = 0; n < 8; n++) oacc[n] *= rsc;
      m = nm;
    }
    float psum = 0.0f;
    #pragma unroll
    for (int nb = 0; nb < 4; nb++)
      #pragma unroll
      for (int r = 0; r < 4; r++) {
        float p = fexp2(plog[nb][r] - m);
        plog[nb][r] = p;
        psum += p;
      }
    psum += __shfl_xor(psum, 16);
    psum += __shfl_xor(psum, 32);
    l += psum;

    // ---- pack P to bf16 pairs (lane-local PV B-fragment) ----
    unsigned pk[4][2];
    #pragma unroll
    for (int nb = 0; nb < 4; nb++) {
      asm("v_cvt_pk_bf16_f32 %0, %1, %2"
          : "=v"(pk[nb][0]) : "v"(plog[nb][0]), "v"(plog[nb][1]));
      asm("v_cvt_pk_bf16_f32 %0, %1, %2"
          : "=v"(pk[nb][1]) : "v"(plog[nb][2]), "v"(plog[nb][3]));
    }

    // ---- O^T += V'(pre-permuted) @ P^T ----
    union U16 { i32x4 i; short8 s; };
    __builtin_amdgcn_s_setprio(1);
    #pragma unroll
    for (int ks2 = 0; ks2 < 2; ks2++) {
      U16 b;
      b.i[0] = (int)pk[2 * ks2][0];
      b.i[1] = (int)pk[2 * ks2][1];
      b.i[2] = (int)pk[2 * ks2 + 1][0];
      b.i[3] = (int)pk[2 * ks2 + 1][1];
      #pragma unroll
      for (int nb2 = 0; nb2 < 8; nb2++) {
        short8 vf = *(const short8*)&Vs[cb][16 * nb2 + l15][32 * ks2 + 8 * g];
        oacc[nb2] = __builtin_amdgcn_mfma_f32_16x16x32_bf16(vf, b.s, oacc[nb2], 0, 0, 0);
      }
    }
    __builtin_amdgcn_s_setprio(0);
    cb ^= 1;
  }

  // write unnormalized partial + (m, l);  lane holds O[q=l15][d=16nb2+4g+r]
  {
    float* op = Opart + ((size_t)seg * NPTS + qrow) * CH;
    #pragma unroll
    for (int nb2 = 0; nb2 < 8; nb2++)
      *(f32x4*)(op + 16 * nb2 + 4 * g) = oacc[nb2];
    if (g == 0) {
      ML[((size_t)seg * NPTS + qrow) * 2]     = m;
      ML[((size_t)seg * NPTS + qrow) * 2 + 1] = l;
    }
  }
}

// ---------------------------------------------------------------------------
// Kernel 4b: combine the NS partials (vectorized: 8 rows/block, float4/lane).
// ---------------------------------------------------------------------------
__global__ __launch_bounds__(256) void k_attn_combine(
    const float* __restrict__ Opart, const float* __restrict__ ML,
    float* __restrict__ out, int NS) {
  const int tid = threadIdx.x;
  const int row = blockIdx.x * 8 + (tid >> 5);
  const int c4 = (tid & 31) * 4;
  float M = -1e30f;
  for (int s = 0; s < NS; s++)
    M = fmaxf(M, ML[((size_t)s * NPTS + row) * 2]);
  float L = 0.0f;
  f32x4 acc = (f32x4){0.f, 0.f, 0.f, 0.f};
  for (int s = 0; s < NS; s++) {
    float ms = ML[((size_t)s * NPTS + row) * 2];
    float ls = ML[((size_t)s * NPTS + row) * 2 + 1];
    float wsc = fexp2(ms - M);
    L += wsc * ls;
    f32x4 o = *(const f32x4*)&Opart[((size_t)s * NPTS + row) * CH + c4];
    acc[0] = fmaf(wsc, o[0], acc[0]);
    acc[1] = fmaf(wsc, o[1], acc[1]);
    acc[2] = fmaf(wsc, o[2], acc[2]);
    acc[3] = fmaf(wsc, o[3], acc[3]);
  }
  float inv = 1.0f / L;
  f32x4 r = acc * (f32x4){inv, inv, inv, inv};
  *(f32x4*)&out[(size_t)row * CH + c4] = r;
}

// ---------------------------------------------------------------------------
// Kernel 6: final row normalize + classifier MLP + sigmoid
// ---------------------------------------------------------------------------
__global__ __launch_bounds__(128) void k_final(
    const float* __restrict__ F,
    const float* __restrict__ c1W, const float* __restrict__ c1b,
    const float* __restrict__ c2W, const float* __restrict__ c2b,
    const float* __restrict__ c3W, const float* __restrict__ c3b,
    float* __restrict__ out) {
  const int row = blockIdx.x, j = threadIdx.x;
  __shared__ float xs[CH];
  __shared__ float h1[32];
  __shared__ float h2[32];
  __shared__ float red[2];
  float x = F[row * CH + j];
  float ss = x * x;
  #pragma unroll
  for (int o = 32; o; o >>= 1) ss += __shfl_xor(ss, o);
  if ((j & 63) == 0) red[j >> 6] = ss;
  __syncthreads();
  float norm = sqrtf(red[0] + red[1]);
  float xn = x / fmaxf(norm, 1e-12f);
  xs[j] = xn;
  out[row * CH + j] = xn;
  __syncthreads();
  if (j < 32) {
    float a = c1b[j];
    for (int kk = 0; kk < CH; kk++) a = fmaf(xs[kk], c1W[kk * 32 + j], a);
    h1[j] = fmaxf(a, 0.0f);
  }
  __syncthreads();
  if (j < 32) {
    float a = c2b[j];
    #pragma unroll
    for (int kk = 0; kk < 32; kk++) a = fmaf(h1[kk], c2W[kk * 32 + j], a);
    h2[j] = fmaxf(a, 0.0f);
  }
  __syncthreads();
  if (j == 0) {
    float a = c3b[0];
    #pragma unroll
    for (int kk = 0; kk < 32; kk++) a = fmaf(h2[kk], c3W[kk], a);
    out[NPTS * CH + row] = 1.0f / (1.0f + __expf(-a));
  }
}

// ---------------------------------------------------------------------------
extern "C" void kernel_launch(void* const* d_in, const int* in_sizes, int n_in,
                              void* d_out, int out_size, void* d_ws, size_t ws_size,
                              hipStream_t stream) {
  const float* refp = (const float*)d_in[0];
  const float* srcp = (const float*)d_in[1];
  const float* cf   = (const float*)d_in[2];
  const float* Win  = (const float*)d_in[3];
  const float* bin  = (const float*)d_in[4];
  const float* mlpW = (const float*)d_in[5];
  const float* mlpb = (const float*)d_in[6];
  const float* mlpg = (const float*)d_in[7];
  const float* mlpbeta = (const float*)d_in[8];
  const float* Wq = (const float*)d_in[9];
  const float* bq = (const float*)d_in[10];
  const float* Wk = (const float*)d_in[11];
  const float* bk = (const float*)d_in[12];
  const float* Wv = (const float*)d_in[13];
  const float* bv = (const float*)d_in[14];
  const float* Wo = (const float*)d_in[15];
  const float* bo = (const float*)d_in[16];
  const float* lng = (const float*)d_in[17];
  const float* lnb = (const float*)d_in[18];
  const float* c1W = (const float*)d_in[19];
  const float* c1b = (const float*)d_in[20];
  const float* c2W = (const float*)d_in[21];
  const float* c2b = (const float*)d_in[22];
  const float* c3W = (const float*)d_in[23];
  const float* c3b = (const float*)d_in[24];
  float* out = (float*)d_out;

  const size_t NC = (size_t)NPTS * CH;
  float* F = (float*)d_ws;
  float* T = F + NC;
  float* A = T + NC;
  ushort* Qb  = (ushort*)(A + NC);
  ushort* Kb  = Qb + NC;
  ushort* Vtb = Kb + NC;
  float* Opart = (float*)(Vtb + NC);

  // pick largest KV-split that fits the workspace
  const size_t base_bytes = 3 * NC * 4 + 3 * NC * 2;
  int NS = 1;
  for (int cand = 16; cand >= 2; cand >>= 1) {
    size_t need = base_bytes + (size_t)cand * (NC * 4 + NPTS * 8);
    if (need <= ws_size) { NS = cand; break; }
  }
  float* ML = Opart + (size_t)NS * NC;
  const int ntiles = NPTS / 64 / NS;

  k_embed<<<NPTS, 128, 0, stream>>>(refp, srcp, cf, Win, bin, F);
  for (int i = 0; i < 3; i++) {
    const int o2 = i * CH * CH, o1 = i * CH;
    k_row_linear_ln<false, true><<<NPTS / 4, 128, 0, stream>>>(
        F, mlpW + o2, mlpb + o1, mlpg + o1, mlpbeta + o1, nullptr, T);
    k_qkv<<<NPTS / 4, 128, 0, stream>>>(
        T, Wq + o2, bq + o1, Wk + o2, bk + o1, Wv + o2, bv + o1, Qb, Kb, Vtb);
    dim3 agrid(NPTS / 128, NS);
    k_attn_mfma<<<agrid, 512, 0, stream>>>(Qb, Kb, Vtb, refp, srcp, Opart, ML, ntiles);
    k_attn_combine<<<NPTS / 8, 256, 0, stream>>>(Opart, ML, A, NS);
    k_row_linear_ln<true, false><<<NPTS / 4, 128, 0, stream>>>(
        A, Wo + o2, bo + o1, lng + o1, lnb + o1, T, F);
  }
  k_final<<<NPTS, 128, 0, stream>>>(F, c1W, c1b, c2W, c2b, c3W, c3b, out);
}